// Round 9
// baseline (255.766 us; speedup 1.0000x reference)
//
#include <hip/hip_runtime.h>
#include <hip/hip_bf16.h>

// ---------------------------------------------------------------------------
// AttentionBlock: B=8, L=1024, C=1024, H=8, ch=128.
// fp32 I/O, bf16 MFMA internal.
// R8: scattered 2B global stores amplify HBM writes ~10x.
// R13/R14: XCD band swizzle -> 49MB fetch; 1-block/CU lockstep caps util.
// R15: 128x128 tile 2-deep counted-vmcnt pipeline = 878 TF structure ceiling.
// R16: partial phase-schedule port regressed.  Do not re-roll from prose.
// R17: V^T epilogue fusion impossible (raw reshape: g=b*8+(l>>7),
//      s=(l&127)*8+(c>>7), d=c&127 -> seq-stride-8 scatter).
// R18: 241.1us (gemm_out 2-deep port in).  R19: attn dbuf+vmcnt: only -2.2us
//      (80KB LDS -> 1 block/CU, one barrier group -- R14 lesson replayed).
// R20: kill transpose_head (kernel + 33.6MB HBM round-trip).  attn reg-stages
//      raw V (L2-resident) and scatters into the swizzled Vt LDS layout with
//      16x ds_write_u16/thread (2-way bank = free, m136).  T14 split: V-loads
//      issue with K gload_lds, writes land between the existing barriers,
//      shared vmcnt(4) ledger.  attn output -> vtbuf (race-free), gemm_out
//      reads A from vtbuf (same flat semantics, passing 8 rounds).
// ---------------------------------------------------------------------------

typedef __attribute__((ext_vector_type(8))) short short8;
typedef __attribute__((ext_vector_type(4))) float f32x4;

#define QK_SCALE 0.29730177875068026f  // 128^-0.25

__device__ __forceinline__ float bf2f(ushort u) {
    union { float f; unsigned int i; } c; c.i = ((unsigned int)u) << 16; return c.f;
}
__device__ __forceinline__ ushort f2bf(float f) {
    union { float f; unsigned int i; } c; c.f = f;
    unsigned int x = c.i;
    return (ushort)((x + 0x7FFFu + ((x >> 16) & 1u)) >> 16);  // RNE
}

// async 16B global->LDS (m97; LDS dest must be wave-uniform base + lane*16)
__device__ __forceinline__ void gload_lds16(const ushort* g, ushort* l) {
    __builtin_amdgcn_global_load_lds(
        (const __attribute__((address_space(1))) unsigned int*)g,
        (__attribute__((address_space(3))) unsigned int*)l, 16, 0, 0);
}

// ---------------------------------------------------------------------------
// Prep kernel: LN row-per-wave (blocks 0..2047, 4 rows/block, no barriers)
// + w_qkv transpose tiles (2048..5119) + w_out transpose (5120..6143).
// ---------------------------------------------------------------------------
__global__ __launch_bounds__(256) void prep_kernel(
    const float* __restrict__ x, const float* __restrict__ g,
    const float* __restrict__ b, ushort* __restrict__ xn,
    const float* __restrict__ w_qkv, ushort* __restrict__ wqkvT,
    const float* __restrict__ w_out, ushort* __restrict__ woutT) {
    __shared__ ushort t[32][33];
    int bid = blockIdx.x;
    int tid = threadIdx.x;
    if (bid < 2048) {
        // ---- LayerNorm: one row per wave ----
        int w = tid >> 6, lane = tid & 63;
        int row = bid * 4 + w;
        const float* xr = x + (size_t)row * 1024;
        float v[4][4];
        float s1 = 0.f, s2 = 0.f;
#pragma unroll
        for (int j = 0; j < 4; j++) {
            float4 t4 = *(const float4*)(xr + lane * 4 + j * 256);
            v[j][0] = t4.x; v[j][1] = t4.y; v[j][2] = t4.z; v[j][3] = t4.w;
#pragma unroll
            for (int e = 0; e < 4; e++) { s1 += v[j][e]; s2 += v[j][e] * v[j][e]; }
        }
#pragma unroll
        for (int m = 32; m >= 1; m >>= 1) { s1 += __shfl_xor(s1, m); s2 += __shfl_xor(s2, m); }
        float mu = s1 * (1.0f / 1024.0f);
        float var = s2 * (1.0f / 1024.0f) - mu * mu;
        float rs = rsqrtf(var + 1e-5f);
#pragma unroll
        for (int j = 0; j < 4; j++) {
            int c0 = lane * 4 + j * 256;
            float4 gg = *(const float4*)(g + c0);
            float4 bb = *(const float4*)(b + c0);
            float gA[4] = {gg.x, gg.y, gg.z, gg.w};
            float bA[4] = {bb.x, bb.y, bb.z, bb.w};
            ushort o[4];
#pragma unroll
            for (int e = 0; e < 4; e++) o[e] = f2bf((v[j][e] - mu) * rs * gA[e] + bA[e]);
            uint2 pk;
            pk.x = (uint)o[0] | ((uint)o[1] << 16);
            pk.y = (uint)o[2] | ((uint)o[3] << 16);
            *(uint2*)(xn + (size_t)row * 1024 + c0) = pk;
        }
    } else {
        // ---- weight transpose tile ----
        const float* in; ushort* out; int R, Cc, bx, by;
        if (bid < 5120) {
            int tt = bid - 2048;
            in = w_qkv; out = wqkvT; R = 1024; Cc = 3072;
            bx = (tt % 96) * 32; by = (tt / 96) * 32;
        } else {
            int tt = bid - 5120;
            in = w_out; out = woutT; R = 1024; Cc = 1024;
            bx = (tt % 32) * 32; by = (tt / 32) * 32;
        }
        int tx = tid & 31, ty = tid >> 5;
#pragma unroll
        for (int j = 0; j < 32; j += 8)
            t[ty + j][tx] = f2bf(in[(size_t)(by + ty + j) * Cc + bx + tx]);
        __syncthreads();
#pragma unroll
        for (int j = 0; j < 32; j += 8)
            out[(size_t)(bx + ty + j) * R + by + tx] = t[tx][ty + j];
    }
}

// ---------------------------------------------------------------------------
// QKV GEMM R15 (proven): C[8192,3072] = A[8192,1024] @ Bt[3072,1024]^T.
// 128x128 tile, BK=64, 256 thr = 4 waves.  LDS 64 KB -> 2 blocks/CU.
// 2-deep counted-vmcnt pipeline, vmcnt(8).  XOR-8 swizzle (conflict-free).
// Grid 1536 = 2/CU x 3 waves.  XCD x owns M-tiles [8x,8x+8), N-fastest.
// ---------------------------------------------------------------------------
__device__ __forceinline__ void stage8(const ushort* __restrict__ Ab,
                                       const ushort* __restrict__ Bb, int t2,
                                       ushort* AsD, ushort* BsD, int tid) {
    const ushort* As_src = Ab + t2 * 64;
    const ushort* Bs_src = Bb + t2 * 64;
#pragma unroll
    for (int i = 0; i < 4; i++) {
        int lin = i * 256 + tid;             // 0..1023: 16B chunk id of A tile
        int r = lin >> 3, p = lin & 7;
        int l = p ^ (r & 7);                 // logical chunk at phys slot p
        gload_lds16(As_src + (size_t)r * 1024 + l * 8, &AsD[lin * 8]);
    }
#pragma unroll
    for (int i = 0; i < 4; i++) {
        int lin = i * 256 + tid;             // 0..1023: chunk id of B tile
        int r = lin >> 3, p = lin & 7;
        int l = p ^ (r & 7);
        gload_lds16(Bs_src + (size_t)r * 1024 + l * 8, &BsD[lin * 8]);
    }
}

__global__ __launch_bounds__(256, 2) void gemm_qkv(
    const ushort* __restrict__ A, const ushort* __restrict__ Bt,
    const float* __restrict__ bias, ushort* __restrict__ out0,
    ushort* __restrict__ out1, ushort* __restrict__ out2) {
    __shared__ __align__(16) ushort As[2][128 * 64];  // 32 KB
    __shared__ __align__(16) ushort Bs[2][128 * 64];  // 32 KB

    int tid = threadIdx.x;
    int lane = tid & 63, w = tid >> 6;       // 4 waves
    int l15 = lane & 15, q4 = lane >> 4;
    int wrM = (w >> 1) * 64;                 // wave M offset: 0/64
    int wcN = (w & 1) * 64;                  // wave N offset: 0/64

    int bid = blockIdx.x;
    int xcd = bid & 7;
    int i = bid >> 3;                        // 0..191
    int by = xcd * 8 + (i & 7);              // M-tile 0..63
    int bx = i >> 3;                         // N-tile 0..23
    int rowBase = by * 128, colBase = bx * 128;

    const ushort* Ab = A + (size_t)rowBase * 1024;
    const ushort* Bb = Bt + (size_t)colBase * 1024;

    f32x4 acc[4][4];
    f32x4 zero = {0.f, 0.f, 0.f, 0.f};
#pragma unroll
    for (int mi = 0; mi < 4; mi++)
#pragma unroll
        for (int ni = 0; ni < 4; ni++) acc[mi][ni] = zero;

    // prologue: fill both buffers, wait only for buf0 (K1 stays in flight)
    stage8(Ab, Bb, 0, &As[0][0], &Bs[0][0], tid);
    stage8(Ab, Bb, 1, &As[1][0], &Bs[1][0], tid);
    asm volatile("s_waitcnt vmcnt(8)" ::: "memory");
    __builtin_amdgcn_s_barrier();

    for (int t = 0; t < 16; ++t) {
        const int cur = t & 1;
        const ushort* Ac = &As[cur][0];
        const ushort* Bc = &Bs[cur][0];

        // ---- read all 16 fragments of this K-tile into registers ----
        short8 aF[4][2], bF[4][2];
#pragma unroll
        for (int kk = 0; kk < 2; kk++) {
#pragma unroll
            for (int mi = 0; mi < 4; mi++) {
                int r = wrM + mi * 16 + l15;
                aF[mi][kk] = *(const short8*)&Ac[r * 64 + ((kk * 4 + q4) ^ (r & 7)) * 8];
            }
#pragma unroll
            for (int ni = 0; ni < 4; ni++) {
                int r = wcN + ni * 16 + l15;
                bF[ni][kk] = *(const short8*)&Bc[r * 64 + ((kk * 4 + q4) ^ (r & 7)) * 8];
            }
        }

        // ---- MFMA kk=0 ----
        __builtin_amdgcn_s_setprio(1);
#pragma unroll
        for (int mi = 0; mi < 4; mi++)
#pragma unroll
            for (int ni = 0; ni < 4; ni++)
                acc[mi][ni] = __builtin_amdgcn_mfma_f32_16x16x32_bf16(
                    aF[mi][0], bF[ni][0], acc[mi][ni], 0, 0, 0);
        __builtin_amdgcn_s_setprio(0);

        // all 16 reads sampled -> buf[cur] free for restaging (block-wide)
        asm volatile("s_waitcnt lgkmcnt(0)" ::: "memory");
        __builtin_amdgcn_s_barrier();
        if (t < 14) stage8(Ab, Bb, t + 2, &As[cur][0], &Bs[cur][0], tid);

        // ---- MFMA kk=1 (hides the stage issue + in-flight loads) ----
        __builtin_amdgcn_s_setprio(1);
#pragma unroll
        for (int mi = 0; mi < 4; mi++)
#pragma unroll
            for (int ni = 0; ni < 4; ni++)
                acc[mi][ni] = __builtin_amdgcn_mfma_f32_16x16x32_bf16(
                    aF[mi][1], bF[ni][1], acc[mi][ni], 0, 0, 0);
        __builtin_amdgcn_s_setprio(0);

        if (t < 15) {
            if (t < 14) asm volatile("s_waitcnt vmcnt(8)" ::: "memory");
            else        asm volatile("s_waitcnt vmcnt(0)" ::: "memory");
            __builtin_amdgcn_s_barrier();
        }
    }

    // C layout: col = lane&15, row = (lane>>4)*4 + r  [m89/m91]
#pragma unroll
    for (int ni = 0; ni < 4; ni++) {
        int col = colBase + wcN + ni * 16 + l15;
        float bv = bias[col];
        float sc = (col < 2048) ? QK_SCALE : 1.0f;
        int bsel = col >> 10, cc = col & 1023;
        ushort* dst = (bsel == 0) ? out0 : ((bsel == 1) ? out1 : out2);
#pragma unroll
        for (int mi = 0; mi < 4; mi++) {
            f32x4 a = acc[mi][ni];
#pragma unroll
            for (int r = 0; r < 4; r++) {
                int row = rowBase + wrM + mi * 16 + q4 * 4 + r;
                dst[(size_t)row * 1024 + cc] = f2bf((a[r] + bv) * sc);
            }
        }
    }
}

// ---------------------------------------------------------------------------
// Out-proj GEMM R18: outf[8192,1024] = A @ woutT^T + bias + resid (fp32 out).
// R15 2-deep structure: 128x128 tile, 256 thr, 64KB LDS, vmcnt(8) pipeline.
// Grid 512 = exactly 2/CU.  XCD x owns M-tiles [8x,8x+8), N-fastest.
// ---------------------------------------------------------------------------
__global__ __launch_bounds__(256, 2) void gemm_out(
    const ushort* __restrict__ A, const ushort* __restrict__ Bt,
    const float* __restrict__ bias, const ushort* __restrict__ resid,
    float* __restrict__ outf) {
    __shared__ __align__(16) ushort As[2][128 * 64];  // 32 KB
    __shared__ __align__(16) ushort Bs[2][128 * 64];  // 32 KB

    int tid = threadIdx.x;
    int lane = tid & 63, w = tid >> 6;       // 4 waves
    int l15 = lane & 15, q4 = lane >> 4;
    int wrM = (w >> 1) * 64;
    int wcN = (w & 1) * 64;

    int bid = blockIdx.x;
    int xcd = bid & 7;
    int i = bid >> 3;                        // 0..63
    int by = xcd * 8 + (i & 7);              // M-tile 0..63
    int bx = i >> 3;                         // N-tile 0..7
    int rowBase = by * 128, colBase = bx * 128;

    const ushort* Ab = A + (size_t)rowBase * 1024;
    const ushort* Bb = Bt + (size_t)colBase * 1024;

    f32x4 acc[4][4];
    f32x4 zero = {0.f, 0.f, 0.f, 0.f};
#pragma unroll
    for (int mi = 0; mi < 4; mi++)
#pragma unroll
        for (int ni = 0; ni < 4; ni++) acc[mi][ni] = zero;

    stage8(Ab, Bb, 0, &As[0][0], &Bs[0][0], tid);
    stage8(Ab, Bb, 1, &As[1][0], &Bs[1][0], tid);
    asm volatile("s_waitcnt vmcnt(8)" ::: "memory");
    __builtin_amdgcn_s_barrier();

    for (int t = 0; t < 16; ++t) {
        const int cur = t & 1;
        const ushort* Ac = &As[cur][0];
        const ushort* Bc = &Bs[cur][0];

        short8 aF[4][2], bF[4][2];
#pragma unroll
        for (int kk = 0; kk < 2; kk++) {
#pragma unroll
            for (int mi = 0; mi < 4; mi++) {
                int r = wrM + mi * 16 + l15;
                aF[mi][kk] = *(const short8*)&Ac[r * 64 + ((kk * 4 + q4) ^ (r & 7)) * 8];
            }
#pragma unroll
            for (int ni = 0; ni < 4; ni++) {
                int r = wcN + ni * 16 + l15;
                bF[ni][kk] = *(const short8*)&Bc[r * 64 + ((kk * 4 + q4) ^ (r & 7)) * 8];
            }
        }

        __builtin_amdgcn_s_setprio(1);
#pragma unroll
        for (int mi = 0; mi < 4; mi++)
#pragma unroll
            for (int ni = 0; ni < 4; ni++)
                acc[mi][ni] = __builtin_amdgcn_mfma_f32_16x16x32_bf16(
                    aF[mi][0], bF[ni][0], acc[mi][ni], 0, 0, 0);
        __builtin_amdgcn_s_setprio(0);

        asm volatile("s_waitcnt lgkmcnt(0)" ::: "memory");
        __builtin_amdgcn_s_barrier();
        if (t < 14) stage8(Ab, Bb, t + 2, &As[cur][0], &Bs[cur][0], tid);

        __builtin_amdgcn_s_setprio(1);
#pragma unroll
        for (int mi = 0; mi < 4; mi++)
#pragma unroll
            for (int ni = 0; ni < 4; ni++)
                acc[mi][ni] = __builtin_amdgcn_mfma_f32_16x16x32_bf16(
                    aF[mi][1], bF[ni][1], acc[mi][ni], 0, 0, 0);
        __builtin_amdgcn_s_setprio(0);

        if (t < 15) {
            if (t < 14) asm volatile("s_waitcnt vmcnt(8)" ::: "memory");
            else        asm volatile("s_waitcnt vmcnt(0)" ::: "memory");
            __builtin_amdgcn_s_barrier();
        }
    }

#pragma unroll
    for (int ni = 0; ni < 4; ni++) {
        int col = colBase + wcN + ni * 16 + l15;
        float bv = bias[col];
#pragma unroll
        for (int mi = 0; mi < 4; mi++) {
            f32x4 a = acc[mi][ni];
#pragma unroll
            for (int r = 0; r < 4; r++) {
                int row = rowBase + wrM + mi * 16 + q4 * 4 + r;
                outf[(size_t)row * 1024 + col] =
                    a[r] + bv + bf2f(resid[(size_t)row * 1024 + col]);
            }
        }
    }
}

// ---------------------------------------------------------------------------
// Attention R20: one block = (head g, 128 q-rows); 8 waves x 16q; 512 thr.
// LDS 80 KB: Ks[2] + Vt[2] dbuf + Ps.  2-deep counted-vmcnt pipeline.
// V is now read DIRECTLY from the raw row-major scratch (transpose_head
// eliminated).  Raw-reshape algebra (R17-verified): head g's V tile kt is
// raw rows [128g + kt*8 + (key>>3)], cc = (key&7)*128 + d.  Per thread:
// key=lane, d0=w*8 (wave-uniform): 2x 16B reg loads (L2-resident via XCD
// head-group swizzle) + 16x ds_write_u16 scattered into the SWIZZLED Vt
// layout (addr = d*64 + ((key>>3)^(d&7))*8 + (key&7)); per-inst banks =
// 2-way = free (m136).  T14 split: loads issue with K gload_lds (shared
// vmcnt(4) ledger), writes land between the two barriers.
// Output -> vtbuf (attnb still holds raw V for slower same-head blocks).
// ---------------------------------------------------------------------------
__device__ __forceinline__ void stageK(const ushort* __restrict__ Kh, int kt,
                                       ushort* KsD, int tid) {
#pragma unroll
    for (int i = 0; i < 2; i++) {
        int linear = i * 512 + tid;          // 0..1023, wave-contiguous
        int r = linear >> 4, p = linear & 15;
        int l = p ^ (r & 15);
        gload_lds16(&Kh[(size_t)(kt * 64 + r) * 128 + l * 8], &KsD[linear * 8]);
    }
}

__device__ __forceinline__ void writeV(ushort* VtD, int vkey, int vd0,
                                       uint4 lo, uint4 hi) {
    uint wl[4] = {lo.x, lo.y, lo.z, lo.w};
    uint wh[4] = {hi.x, hi.y, hi.z, hi.w};
    int c8 = (vkey >> 3);
    int k7 = (vkey & 7);
#pragma unroll
    for (int j = 0; j < 8; j++) {
        int d = vd0 + j;
        int p = (c8 ^ (d & 7)) << 3;
        VtD[d * 64 + p + k7] = (ushort)(wl[j >> 1] >> ((j & 1) * 16));
        VtD[(d + 64) * 64 + p + k7] = (ushort)(wh[j >> 1] >> ((j & 1) * 16));
    }
}

__global__ __launch_bounds__(512) void attn_kernel(
    const ushort* __restrict__ qb, const ushort* __restrict__ kb,
    const ushort* __restrict__ vraw, ushort* __restrict__ ob) {
    // XCD head-grouping: XCD x (bid&7) owns heads 8x..8x+7, all 8 q-blocks.
    int bid = blockIdx.x;
    int xcd = bid & 7, ii = bid >> 3;        // ii 0..63
    int g = xcd * 8 + (ii >> 3);             // head 0..63
    int qblk = ii & 7;                       // 128-row q block
    const ushort* Qh = qb + (size_t)g * 131072;
    const ushort* Kh = kb + (size_t)g * 131072;

    __shared__ __align__(16) ushort Ks[2][64 * 128];   // 32 KB
    __shared__ __align__(16) ushort Vt[2][128 * 64];   // 32 KB
    __shared__ __align__(16) ushort Ps[128 * 64];      // 16 KB

    int tid = threadIdx.x, lane = tid & 63, w = tid >> 6;  // w in [0,8)
    int l15 = lane & 15, q4 = lane >> 4;
    int q0 = qblk * 128;

    // V reg-staging geometry (raw rows 128g.. of [8192][1024] scratch):
    int vkey = lane;                 // key within kt-tile
    int vd0 = w * 8;                 // wave-uniform d block (lo half)
    const ushort* vsrc = vraw + (size_t)(128 * g + (vkey >> 3)) * 1024
                              + (vkey & 7) * 128 + vd0;
    // per-tile advance: 8 raw rows = 8192 ushorts

    // Q A-fragments: A[m=l15][k = ks*32 + q4*8 + j]
    short8 qf[4];
#pragma unroll
    for (int ks = 0; ks < 4; ks++)
        qf[ks] = *(const short8*)&Qh[(size_t)(q0 + w * 16 + l15) * 128 + ks * 32 + q4 * 8];

    f32x4 zero = {0.f, 0.f, 0.f, 0.f};
    f32x4 o[8];
#pragma unroll
    for (int ni = 0; ni < 8; ni++) o[ni] = zero;
    float plsum[4] = {0.f, 0.f, 0.f, 0.f};

    // prologue: K0->Ks0, V0->eRegs, K1->Ks1, V1->oRegs; drain K0,V0.
    uint4 eLo, eHi, oLo, oHi;
    stageK(Kh, 0, &Ks[0][0], tid);
    eLo = *(const uint4*)(vsrc);
    eHi = *(const uint4*)(vsrc + 64);
    stageK(Kh, 1, &Ks[1][0], tid);
    oLo = *(const uint4*)(vsrc + 8192);
    oHi = *(const uint4*)(vsrc + 8192 + 64);
    asm volatile("s_waitcnt vmcnt(4)" ::: "memory");   // K0 + V0 landed
    writeV(&Vt[0][0], vkey, vd0, eLo, eHi);
    asm volatile("s_waitcnt lgkmcnt(0)" ::: "memory");
    __builtin_amdgcn_s_barrier();

    for (int kt = 0; kt < 16; kt++) {
        const int cur = kt & 1;
        const ushort* Kc = &Ks[cur][0];
        const ushort* Vc = &Vt[cur][0];

        // S = Q K^T : 16q x 64key per wave
        f32x4 sacc[4];
#pragma unroll
        for (int ni = 0; ni < 4; ni++) sacc[ni] = zero;
        __builtin_amdgcn_s_setprio(1);
#pragma unroll
        for (int ks = 0; ks < 4; ks++) {
#pragma unroll
            for (int ni = 0; ni < 4; ni++) {
                int r = ni * 16 + l15;
                int p = (ks * 4 + q4) ^ (r & 15);
                short8 bF = *(const short8*)&Kc[r * 128 + p * 8];
                sacc[ni] = __builtin_amdgcn_mfma_f32_16x16x32_bf16(
                    qf[ks], bF, sacc[ni], 0, 0, 0);
            }
        }
        __builtin_amdgcn_s_setprio(0);

        // P = exp(S) -> Ps (swizzled); accumulate per-lane partial row sums
#pragma unroll
        for (int ni = 0; ni < 4; ni++) {
#pragma unroll
            for (int r = 0; r < 4; r++) {
                float pv = __expf(sacc[ni][r]);
                plsum[r] += pv;
                int qloc = w * 16 + q4 * 4 + r;       // wave-private rows
                int key = ni * 16 + l15;
                int pc = (key >> 3) ^ (qloc & 7);
                Ps[qloc * 64 + pc * 8 + (key & 7)] = f2bf(pv);
            }
        }

        // O += P V  (wave-private Ps rows; same-wave RAW handled by waitcnt)
        __builtin_amdgcn_s_setprio(1);
#pragma unroll
        for (int ks2 = 0; ks2 < 2; ks2++) {
            int c = ks2 * 4 + q4;
            int row = w * 16 + l15;                   // row&7 == l15&7
            short8 aF = *(const short8*)&Ps[row * 64 + (c ^ (l15 & 7)) * 8];
#pragma unroll
            for (int ni = 0; ni < 8; ni++) {
                int d = ni * 16 + l15;
                short8 bF = *(const short8*)&Vc[d * 64 + (c ^ (d & 7)) * 8];
                o[ni] = __builtin_amdgcn_mfma_f32_16x16x32_bf16(aF, bF, o[ni], 0, 0, 0);
            }
        }
        __builtin_amdgcn_s_setprio(0);

        // ---- bufs free after barrier; stage kt+2; drain kt+1; write V ----
        asm volatile("s_waitcnt lgkmcnt(0)" ::: "memory");
        __builtin_amdgcn_s_barrier();
        if (kt < 14) {
            stageK(Kh, kt + 2, &Ks[cur][0], tid);
            const ushort* vp = vsrc + (size_t)(kt + 2) * 8192;
            if (cur == 0) { eLo = *(const uint4*)vp; eHi = *(const uint4*)(vp + 64); }
            else          { oLo = *(const uint4*)vp; oHi = *(const uint4*)(vp + 64); }
            asm volatile("s_waitcnt vmcnt(4)" ::: "memory");  // K,V of kt+1 landed
        } else if (kt == 14) {
            asm volatile("s_waitcnt vmcnt(0)" ::: "memory");  // K15,V15 landed
        }
        if (kt < 15) {
            if (cur == 0) writeV(&Vt[1][0], vkey, vd0, oLo, oHi);
            else          writeV(&Vt[0][0], vkey, vd0, eLo, eHi);
            asm volatile("s_waitcnt lgkmcnt(0)" ::: "memory");
            __builtin_amdgcn_s_barrier();
        }
    }

    // row sums: reduce per-lane partials over the 16 l15-lanes
#pragma unroll
    for (int r = 0; r < 4; r++) {
#pragma unroll
        for (int m = 1; m < 16; m <<= 1) plsum[r] += __shfl_xor(plsum[r], m, 16);
    }
    float inv[4];
#pragma unroll
    for (int r = 0; r < 4; r++) inv[r] = 1.0f / plsum[r];
#pragma unroll
    for (int ni = 0; ni < 8; ni++)
#pragma unroll
        for (int r = 0; r < 4; r++) {
            int qrow = q0 + w * 16 + q4 * 4 + r;
            ob[(size_t)g * 131072 + (size_t)qrow * 128 + ni * 16 + l15] =
                f2bf(o[ni][r] * inv[r]);
        }
}

// ---------------------------------------------------------------------------
extern "C" void kernel_launch(void* const* d_in, const int* in_sizes, int n_in,
                              void* d_out, int out_size, void* d_ws, size_t ws_size,
                              hipStream_t stream) {
    const float* x     = (const float*)d_in[0];
    const float* ln_g  = (const float*)d_in[1];
    const float* ln_b  = (const float*)d_in[2];
    const float* w_qkv = (const float*)d_in[3];
    const float* b_qkv = (const float*)d_in[4];
    const float* w_out = (const float*)d_in[5];
    const float* b_out = (const float*)d_in[6];
    float* out = (float*)d_out;

    const size_t MC = 8192ull * 1024ull;  // 8.39M elems
    ushort* xn    = (ushort*)d_ws;
    ushort* wqkvT = xn + MC;
    ushort* woutT = wqkvT + 3072ull * 1024ull;
    ushort* qbuf  = woutT + 1024ull * 1024ull;
    ushort* kbuf  = qbuf + MC;
    ushort* vtbuf = kbuf + MC;        // now: attn OUTPUT buffer
    ushort* attnb = vtbuf + MC;       // raw V scratch (row-major)
    // total: 46.14M ushorts = 92.3 MB (same layout as passing rounds)

    prep_kernel<<<6144, 256, 0, stream>>>(x, ln_g, ln_b, xn, w_qkv, wqkvT, w_out, woutT);
    // q,k -> qbuf,kbuf ; v -> attnb (scratch, row-major coalesced)
    gemm_qkv<<<1536, 256, 0, stream>>>(xn, wqkvT, b_qkv, qbuf, kbuf, attnb);
    // attn reads raw V from attnb (in-kernel transpose), writes to vtbuf
    attn_kernel<<<512, 512, 0, stream>>>(qbuf, kbuf, attnb, vtbuf);
    gemm_out<<<512, 256, 0, stream>>>(vtbuf, woutT, b_out, xn, out);
}

// Round 10
// 240.520 us; speedup vs baseline: 1.0634x; 1.0634x over previous
//
#include <hip/hip_runtime.h>
#include <hip/hip_bf16.h>

// ---------------------------------------------------------------------------
// AttentionBlock: B=8, L=1024, C=1024, H=8, ch=128.
// fp32 I/O, bf16 MFMA internal.
// R8: scattered 2B global stores amplify HBM writes ~10x.
// R13/R14: XCD band swizzle -> 49MB fetch; 1-block/CU lockstep caps util.
// R15: 128x128 tile 2-deep counted-vmcnt pipeline = 878 TF structure ceiling.
// R16: partial phase-schedule port regressed.  R17: V^T gemm-epilogue fusion
//      impossible (raw reshape scatters seq).  R18: gemm_out 2-deep port.
// R19: attn dbuf+vmcnt+setprio+head-group swizzle: 239.0us (best).
// R20 lesson (measured): in-attn V transpose via 16x ds_write_u16/thread =
//      attn 81.5us (MfmaUtil 16.7) -- scalar LDS scatter too slow; net +17us.
//      transpose_head stays.  Also measured: R19 attn ~52-57us, lockstep-
//      bound (80KB LDS, occupancy 21% = one barrier group in practice).
// R21: revert to R19 + attn restructured to QBLK=64 / 256thr / 4 waves,
//      LDS 72KB -> true 2 blocks/CU, two barrier groups desync (R15
//      mechanism).  Same math, same vmcnt(8) ledger as proven GEMMs.
// ---------------------------------------------------------------------------

typedef __attribute__((ext_vector_type(8))) short short8;
typedef __attribute__((ext_vector_type(4))) float f32x4;

#define QK_SCALE 0.29730177875068026f  // 128^-0.25

__device__ __forceinline__ float bf2f(ushort u) {
    union { float f; unsigned int i; } c; c.i = ((unsigned int)u) << 16; return c.f;
}
__device__ __forceinline__ ushort f2bf(float f) {
    union { float f; unsigned int i; } c; c.f = f;
    unsigned int x = c.i;
    return (ushort)((x + 0x7FFFu + ((x >> 16) & 1u)) >> 16);  // RNE
}

// async 16B global->LDS (m97; LDS dest must be wave-uniform base + lane*16)
__device__ __forceinline__ void gload_lds16(const ushort* g, ushort* l) {
    __builtin_amdgcn_global_load_lds(
        (const __attribute__((address_space(1))) unsigned int*)g,
        (__attribute__((address_space(3))) unsigned int*)l, 16, 0, 0);
}

// ---------------------------------------------------------------------------
// Prep kernel: LN row-per-wave (blocks 0..2047, 4 rows/block, no barriers)
// + w_qkv transpose tiles (2048..5119) + w_out transpose (5120..6143).
// ---------------------------------------------------------------------------
__global__ __launch_bounds__(256) void prep_kernel(
    const float* __restrict__ x, const float* __restrict__ g,
    const float* __restrict__ b, ushort* __restrict__ xn,
    const float* __restrict__ w_qkv, ushort* __restrict__ wqkvT,
    const float* __restrict__ w_out, ushort* __restrict__ woutT) {
    __shared__ ushort t[32][33];
    int bid = blockIdx.x;
    int tid = threadIdx.x;
    if (bid < 2048) {
        // ---- LayerNorm: one row per wave ----
        int w = tid >> 6, lane = tid & 63;
        int row = bid * 4 + w;
        const float* xr = x + (size_t)row * 1024;
        float v[4][4];
        float s1 = 0.f, s2 = 0.f;
#pragma unroll
        for (int j = 0; j < 4; j++) {
            float4 t4 = *(const float4*)(xr + lane * 4 + j * 256);
            v[j][0] = t4.x; v[j][1] = t4.y; v[j][2] = t4.z; v[j][3] = t4.w;
#pragma unroll
            for (int e = 0; e < 4; e++) { s1 += v[j][e]; s2 += v[j][e] * v[j][e]; }
        }
#pragma unroll
        for (int m = 32; m >= 1; m >>= 1) { s1 += __shfl_xor(s1, m); s2 += __shfl_xor(s2, m); }
        float mu = s1 * (1.0f / 1024.0f);
        float var = s2 * (1.0f / 1024.0f) - mu * mu;
        float rs = rsqrtf(var + 1e-5f);
#pragma unroll
        for (int j = 0; j < 4; j++) {
            int c0 = lane * 4 + j * 256;
            float4 gg = *(const float4*)(g + c0);
            float4 bb = *(const float4*)(b + c0);
            float gA[4] = {gg.x, gg.y, gg.z, gg.w};
            float bA[4] = {bb.x, bb.y, bb.z, bb.w};
            ushort o[4];
#pragma unroll
            for (int e = 0; e < 4; e++) o[e] = f2bf((v[j][e] - mu) * rs * gA[e] + bA[e]);
            uint2 pk;
            pk.x = (uint)o[0] | ((uint)o[1] << 16);
            pk.y = (uint)o[2] | ((uint)o[3] << 16);
            *(uint2*)(xn + (size_t)row * 1024 + c0) = pk;
        }
    } else {
        // ---- weight transpose tile ----
        const float* in; ushort* out; int R, Cc, bx, by;
        if (bid < 5120) {
            int tt = bid - 2048;
            in = w_qkv; out = wqkvT; R = 1024; Cc = 3072;
            bx = (tt % 96) * 32; by = (tt / 96) * 32;
        } else {
            int tt = bid - 5120;
            in = w_out; out = woutT; R = 1024; Cc = 1024;
            bx = (tt % 32) * 32; by = (tt / 32) * 32;
        }
        int tx = tid & 31, ty = tid >> 5;
#pragma unroll
        for (int j = 0; j < 32; j += 8)
            t[ty + j][tx] = f2bf(in[(size_t)(by + ty + j) * Cc + bx + tx]);
        __syncthreads();
#pragma unroll
        for (int j = 0; j < 32; j += 8)
            out[(size_t)(bx + ty + j) * R + by + tx] = t[tx][ty + j];
    }
}

// ---------------------------------------------------------------------------
// Per-head bf16 transpose: in [64][1024][128] -> out [64][128][1024]
// (flat-chunk transpose == raw-reshape semantics; correct by construction)
// ---------------------------------------------------------------------------
__global__ __launch_bounds__(256) void transpose_head(
    const ushort* __restrict__ in, ushort* __restrict__ out) {
    __shared__ ushort t[32][33];
    int h = blockIdx.z;
    int j0 = blockIdx.y * 32;  // seq pos
    int d0 = blockIdx.x * 32;  // head dim
    int tx = threadIdx.x & 31, ty = threadIdx.x >> 5;
    const ushort* src = in + (size_t)h * 131072;
    ushort* dst = out + (size_t)h * 131072;
#pragma unroll
    for (int j = 0; j < 32; j += 8)
        t[ty + j][tx] = src[(size_t)(j0 + ty + j) * 128 + d0 + tx];
    __syncthreads();
#pragma unroll
    for (int j = 0; j < 32; j += 8)
        dst[(size_t)(d0 + ty + j) * 1024 + j0 + tx] = t[tx][ty + j];
}

// ---------------------------------------------------------------------------
// QKV GEMM R15 (proven): C[8192,3072] = A[8192,1024] @ Bt[3072,1024]^T.
// 128x128 tile, BK=64, 256 thr = 4 waves.  LDS 64 KB -> 2 blocks/CU.
// 2-deep counted-vmcnt pipeline, vmcnt(8).  XOR-8 swizzle (conflict-free).
// Grid 1536 = 2/CU x 3 waves.  XCD x owns M-tiles [8x,8x+8), N-fastest.
// ---------------------------------------------------------------------------
__device__ __forceinline__ void stage8(const ushort* __restrict__ Ab,
                                       const ushort* __restrict__ Bb, int t2,
                                       ushort* AsD, ushort* BsD, int tid) {
    const ushort* As_src = Ab + t2 * 64;
    const ushort* Bs_src = Bb + t2 * 64;
#pragma unroll
    for (int i = 0; i < 4; i++) {
        int lin = i * 256 + tid;             // 0..1023: 16B chunk id of A tile
        int r = lin >> 3, p = lin & 7;
        int l = p ^ (r & 7);                 // logical chunk at phys slot p
        gload_lds16(As_src + (size_t)r * 1024 + l * 8, &AsD[lin * 8]);
    }
#pragma unroll
    for (int i = 0; i < 4; i++) {
        int lin = i * 256 + tid;             // 0..1023: chunk id of B tile
        int r = lin >> 3, p = lin & 7;
        int l = p ^ (r & 7);
        gload_lds16(Bs_src + (size_t)r * 1024 + l * 8, &BsD[lin * 8]);
    }
}

__global__ __launch_bounds__(256, 2) void gemm_qkv(
    const ushort* __restrict__ A, const ushort* __restrict__ Bt,
    const float* __restrict__ bias, ushort* __restrict__ out0,
    ushort* __restrict__ out1, ushort* __restrict__ out2) {
    __shared__ __align__(16) ushort As[2][128 * 64];  // 32 KB
    __shared__ __align__(16) ushort Bs[2][128 * 64];  // 32 KB

    int tid = threadIdx.x;
    int lane = tid & 63, w = tid >> 6;       // 4 waves
    int l15 = lane & 15, q4 = lane >> 4;
    int wrM = (w >> 1) * 64;                 // wave M offset: 0/64
    int wcN = (w & 1) * 64;                  // wave N offset: 0/64

    int bid = blockIdx.x;
    int xcd = bid & 7;
    int i = bid >> 3;                        // 0..191
    int by = xcd * 8 + (i & 7);              // M-tile 0..63
    int bx = i >> 3;                         // N-tile 0..23
    int rowBase = by * 128, colBase = bx * 128;

    const ushort* Ab = A + (size_t)rowBase * 1024;
    const ushort* Bb = Bt + (size_t)colBase * 1024;

    f32x4 acc[4][4];
    f32x4 zero = {0.f, 0.f, 0.f, 0.f};
#pragma unroll
    for (int mi = 0; mi < 4; mi++)
#pragma unroll
        for (int ni = 0; ni < 4; ni++) acc[mi][ni] = zero;

    // prologue: fill both buffers, wait only for buf0 (K1 stays in flight)
    stage8(Ab, Bb, 0, &As[0][0], &Bs[0][0], tid);
    stage8(Ab, Bb, 1, &As[1][0], &Bs[1][0], tid);
    asm volatile("s_waitcnt vmcnt(8)" ::: "memory");
    __builtin_amdgcn_s_barrier();

    for (int t = 0; t < 16; ++t) {
        const int cur = t & 1;
        const ushort* Ac = &As[cur][0];
        const ushort* Bc = &Bs[cur][0];

        // ---- read all 16 fragments of this K-tile into registers ----
        short8 aF[4][2], bF[4][2];
#pragma unroll
        for (int kk = 0; kk < 2; kk++) {
#pragma unroll
            for (int mi = 0; mi < 4; mi++) {
                int r = wrM + mi * 16 + l15;
                aF[mi][kk] = *(const short8*)&Ac[r * 64 + ((kk * 4 + q4) ^ (r & 7)) * 8];
            }
#pragma unroll
            for (int ni = 0; ni < 4; ni++) {
                int r = wcN + ni * 16 + l15;
                bF[ni][kk] = *(const short8*)&Bc[r * 64 + ((kk * 4 + q4) ^ (r & 7)) * 8];
            }
        }

        // ---- MFMA kk=0 ----
        __builtin_amdgcn_s_setprio(1);
#pragma unroll
        for (int mi = 0; mi < 4; mi++)
#pragma unroll
            for (int ni = 0; ni < 4; ni++)
                acc[mi][ni] = __builtin_amdgcn_mfma_f32_16x16x32_bf16(
                    aF[mi][0], bF[ni][0], acc[mi][ni], 0, 0, 0);
        __builtin_amdgcn_s_setprio(0);

        // all 16 reads sampled -> buf[cur] free for restaging (block-wide)
        asm volatile("s_waitcnt lgkmcnt(0)" ::: "memory");
        __builtin_amdgcn_s_barrier();
        if (t < 14) stage8(Ab, Bb, t + 2, &As[cur][0], &Bs[cur][0], tid);

        // ---- MFMA kk=1 (hides the stage issue + in-flight loads) ----
        __builtin_amdgcn_s_setprio(1);
#pragma unroll
        for (int mi = 0; mi < 4; mi++)
#pragma unroll
            for (int ni = 0; ni < 4; ni++)
                acc[mi][ni] = __builtin_amdgcn_mfma_f32_16x16x32_bf16(
                    aF[mi][1], bF[ni][1], acc[mi][ni], 0, 0, 0);
        __builtin_amdgcn_s_setprio(0);

        if (t < 15) {
            if (t < 14) asm volatile("s_waitcnt vmcnt(8)" ::: "memory");
            else        asm volatile("s_waitcnt vmcnt(0)" ::: "memory");
            __builtin_amdgcn_s_barrier();
        }
    }

    // C layout: col = lane&15, row = (lane>>4)*4 + r  [m89/m91]
#pragma unroll
    for (int ni = 0; ni < 4; ni++) {
        int col = colBase + wcN + ni * 16 + l15;
        float bv = bias[col];
        float sc = (col < 2048) ? QK_SCALE : 1.0f;
        int bsel = col >> 10, cc = col & 1023;
        ushort* dst = (bsel == 0) ? out0 : ((bsel == 1) ? out1 : out2);
#pragma unroll
        for (int mi = 0; mi < 4; mi++) {
            f32x4 a = acc[mi][ni];
#pragma unroll
            for (int r = 0; r < 4; r++) {
                int row = rowBase + wrM + mi * 16 + q4 * 4 + r;
                dst[(size_t)row * 1024 + cc] = f2bf((a[r] + bv) * sc);
            }
        }
    }
}

// ---------------------------------------------------------------------------
// Out-proj GEMM R18: outf[8192,1024] = A @ woutT^T + bias + resid (fp32 out).
// R15 2-deep structure: 128x128 tile, 256 thr, 64KB LDS, vmcnt(8) pipeline.
// Grid 512 = exactly 2/CU.  XCD x owns M-tiles [8x,8x+8), N-fastest.
// ---------------------------------------------------------------------------
__global__ __launch_bounds__(256, 2) void gemm_out(
    const ushort* __restrict__ A, const ushort* __restrict__ Bt,
    const float* __restrict__ bias, const ushort* __restrict__ resid,
    float* __restrict__ outf) {
    __shared__ __align__(16) ushort As[2][128 * 64];  // 32 KB
    __shared__ __align__(16) ushort Bs[2][128 * 64];  // 32 KB

    int tid = threadIdx.x;
    int lane = tid & 63, w = tid >> 6;       // 4 waves
    int l15 = lane & 15, q4 = lane >> 4;
    int wrM = (w >> 1) * 64;
    int wcN = (w & 1) * 64;

    int bid = blockIdx.x;
    int xcd = bid & 7;
    int i = bid >> 3;                        // 0..63
    int by = xcd * 8 + (i & 7);              // M-tile 0..63
    int bx = i >> 3;                         // N-tile 0..7
    int rowBase = by * 128, colBase = bx * 128;

    const ushort* Ab = A + (size_t)rowBase * 1024;
    const ushort* Bb = Bt + (size_t)colBase * 1024;

    f32x4 acc[4][4];
    f32x4 zero = {0.f, 0.f, 0.f, 0.f};
#pragma unroll
    for (int mi = 0; mi < 4; mi++)
#pragma unroll
        for (int ni = 0; ni < 4; ni++) acc[mi][ni] = zero;

    stage8(Ab, Bb, 0, &As[0][0], &Bs[0][0], tid);
    stage8(Ab, Bb, 1, &As[1][0], &Bs[1][0], tid);
    asm volatile("s_waitcnt vmcnt(8)" ::: "memory");
    __builtin_amdgcn_s_barrier();

    for (int t = 0; t < 16; ++t) {
        const int cur = t & 1;
        const ushort* Ac = &As[cur][0];
        const ushort* Bc = &Bs[cur][0];

        short8 aF[4][2], bF[4][2];
#pragma unroll
        for (int kk = 0; kk < 2; kk++) {
#pragma unroll
            for (int mi = 0; mi < 4; mi++) {
                int r = wrM + mi * 16 + l15;
                aF[mi][kk] = *(const short8*)&Ac[r * 64 + ((kk * 4 + q4) ^ (r & 7)) * 8];
            }
#pragma unroll
            for (int ni = 0; ni < 4; ni++) {
                int r = wcN + ni * 16 + l15;
                bF[ni][kk] = *(const short8*)&Bc[r * 64 + ((kk * 4 + q4) ^ (r & 7)) * 8];
            }
        }

        __builtin_amdgcn_s_setprio(1);
#pragma unroll
        for (int mi = 0; mi < 4; mi++)
#pragma unroll
            for (int ni = 0; ni < 4; ni++)
                acc[mi][ni] = __builtin_amdgcn_mfma_f32_16x16x32_bf16(
                    aF[mi][0], bF[ni][0], acc[mi][ni], 0, 0, 0);
        __builtin_amdgcn_s_setprio(0);

        asm volatile("s_waitcnt lgkmcnt(0)" ::: "memory");
        __builtin_amdgcn_s_barrier();
        if (t < 14) stage8(Ab, Bb, t + 2, &As[cur][0], &Bs[cur][0], tid);

        __builtin_amdgcn_s_setprio(1);
#pragma unroll
        for (int mi = 0; mi < 4; mi++)
#pragma unroll
            for (int ni = 0; ni < 4; ni++)
                acc[mi][ni] = __builtin_amdgcn_mfma_f32_16x16x32_bf16(
                    aF[mi][1], bF[ni][1], acc[mi][ni], 0, 0, 0);
        __builtin_amdgcn_s_setprio(0);

        if (t < 15) {
            if (t < 14) asm volatile("s_waitcnt vmcnt(8)" ::: "memory");
            else        asm volatile("s_waitcnt vmcnt(0)" ::: "memory");
            __builtin_amdgcn_s_barrier();
        }
    }

#pragma unroll
    for (int ni = 0; ni < 4; ni++) {
        int col = colBase + wcN + ni * 16 + l15;
        float bv = bias[col];
#pragma unroll
        for (int mi = 0; mi < 4; mi++) {
            f32x4 a = acc[mi][ni];
#pragma unroll
            for (int r = 0; r < 4; r++) {
                int row = rowBase + wrM + mi * 16 + q4 * 4 + r;
                outf[(size_t)row * 1024 + col] =
                    a[r] + bv + bf2f(resid[(size_t)row * 1024 + col]);
            }
        }
    }
}

// ---------------------------------------------------------------------------
// Attention R21: one block = (head g, 64 q-rows); 4 waves x 16q; 256 thr.
// LDS 72 KB: Ks[2] 32K + Vt[2] 32K + Ps 8K -> TRUE 2 blocks/CU (144<=160),
// two independent barrier groups desync (R15 mechanism).  2-deep counted-
// vmcnt pipeline, 8 gloads/thread/stage, vmcnt(8), setprio on MFMA.
// XCD head-grouping: XCD x owns heads 8x..8x+7 (K/V 4MB L2-resident).
//  - Ks [64 key][128 d], XOR-16 chunk swizzle
//  - Vt [128 d][64 key], XOR-8 chunk swizzle
//  - Ps [64 q][64 key], XOR-8 swizzle, wave-private rows
// ---------------------------------------------------------------------------
__device__ __forceinline__ void attn_stage(const ushort* __restrict__ Kh,
                                           const ushort* __restrict__ Vh,
                                           int kt, ushort* KsD, ushort* VtD,
                                           int tid) {
#pragma unroll
    for (int i = 0; i < 4; i++) {
        int linear = i * 256 + tid;          // 0..1023, wave-contiguous
        int r = linear >> 4, p = linear & 15;
        int l = p ^ (r & 15);
        gload_lds16(&Kh[(size_t)(kt * 64 + r) * 128 + l * 8], &KsD[linear * 8]);
    }
#pragma unroll
    for (int i = 0; i < 4; i++) {
        int linear = i * 256 + tid;          // 0..1023
        int d = linear >> 3, p = linear & 7;
        int c = p ^ (d & 7);
        gload_lds16(&Vh[(size_t)d * 1024 + kt * 64 + c * 8], &VtD[linear * 8]);
    }
}

__global__ __launch_bounds__(256, 2) void attn_kernel(
    const ushort* __restrict__ qb, const ushort* __restrict__ kb,
    const ushort* __restrict__ vt, ushort* __restrict__ ob) {
    // XCD head-grouping: XCD x (bid&7) owns heads 8x..8x+7, 16 q-blocks each.
    int bid = blockIdx.x;
    int xcd = bid & 7, ii = bid >> 3;        // ii 0..127
    int g = xcd * 8 + (ii >> 4);             // head 0..63
    int qblk = ii & 15;                      // 64-row q block
    const ushort* Qh = qb + (size_t)g * 131072;
    const ushort* Kh = kb + (size_t)g * 131072;
    const ushort* Vh = vt + (size_t)g * 131072;  // [128 d][1024 key]

    __shared__ __align__(16) ushort Ks[2][64 * 128];   // 32 KB
    __shared__ __align__(16) ushort Vt[2][128 * 64];   // 32 KB
    __shared__ __align__(16) ushort Ps[64 * 64];       //  8 KB

    int tid = threadIdx.x, lane = tid & 63, w = tid >> 6;  // w in [0,4)
    int l15 = lane & 15, q4 = lane >> 4;
    int q0 = qblk * 64;

    // Q A-fragments: A[m=l15][k = ks*32 + q4*8 + j]
    short8 qf[4];
#pragma unroll
    for (int ks = 0; ks < 4; ks++)
        qf[ks] = *(const short8*)&Qh[(size_t)(q0 + w * 16 + l15) * 128 + ks * 32 + q4 * 8];

    f32x4 zero = {0.f, 0.f, 0.f, 0.f};
    f32x4 o[8];
#pragma unroll
    for (int ni = 0; ni < 8; ni++) o[ni] = zero;
    float plsum[4] = {0.f, 0.f, 0.f, 0.f};

    // prologue: stage kt0 -> buf0, kt1 -> buf1; wait only kt0 (8 left)
    attn_stage(Kh, Vh, 0, &Ks[0][0], &Vt[0][0], tid);
    attn_stage(Kh, Vh, 1, &Ks[1][0], &Vt[1][0], tid);
    asm volatile("s_waitcnt vmcnt(8)" ::: "memory");
    __builtin_amdgcn_s_barrier();

    for (int kt = 0; kt < 16; kt++) {
        const int cur = kt & 1;
        const ushort* Kc = &Ks[cur][0];
        const ushort* Vc = &Vt[cur][0];

        // S = Q K^T : 16q x 64key per wave
        f32x4 sacc[4];
#pragma unroll
        for (int ni = 0; ni < 4; ni++) sacc[ni] = zero;
        __builtin_amdgcn_s_setprio(1);
#pragma unroll
        for (int ks = 0; ks < 4; ks++) {
#pragma unroll
            for (int ni = 0; ni < 4; ni++) {
                int r = ni * 16 + l15;
                int p = (ks * 4 + q4) ^ (r & 15);
                short8 bF = *(const short8*)&Kc[r * 128 + p * 8];
                sacc[ni] = __builtin_amdgcn_mfma_f32_16x16x32_bf16(
                    qf[ks], bF, sacc[ni], 0, 0, 0);
            }
        }
        __builtin_amdgcn_s_setprio(0);

        // P = exp(S) -> Ps (swizzled); accumulate per-lane partial row sums
#pragma unroll
        for (int ni = 0; ni < 4; ni++) {
#pragma unroll
            for (int r = 0; r < 4; r++) {
                float pv = __expf(sacc[ni][r]);
                plsum[r] += pv;
                int qloc = w * 16 + q4 * 4 + r;       // wave-private rows
                int key = ni * 16 + l15;
                int pc = (key >> 3) ^ (qloc & 7);
                Ps[qloc * 64 + pc * 8 + (key & 7)] = f2bf(pv);
            }
        }

        // O += P V  (wave-private Ps rows; same-wave RAW handled by waitcnt)
        __builtin_amdgcn_s_setprio(1);
#pragma unroll
        for (int ks2 = 0; ks2 < 2; ks2++) {
            int c = ks2 * 4 + q4;
            int row = w * 16 + l15;                   // row&7 == l15&7
            short8 aF = *(const short8*)&Ps[row * 64 + (c ^ (l15 & 7)) * 8];
#pragma unroll
            for (int ni = 0; ni < 8; ni++) {
                int d = ni * 16 + l15;
                short8 bF = *(const short8*)&Vc[d * 64 + (c ^ (d & 7)) * 8];
                o[ni] = __builtin_amdgcn_mfma_f32_16x16x32_bf16(aF, bF, o[ni], 0, 0, 0);
            }
        }
        __builtin_amdgcn_s_setprio(0);

        // ---- all LDS reads of buf[cur] done -> restage; counted vmcnt ----
        asm volatile("s_waitcnt lgkmcnt(0)" ::: "memory");
        __builtin_amdgcn_s_barrier();
        if (kt < 14) attn_stage(Kh, Vh, kt + 2, &Ks[cur][0], &Vt[cur][0], tid);
        if (kt < 14)       asm volatile("s_waitcnt vmcnt(8)" ::: "memory");
        else if (kt == 14) asm volatile("s_waitcnt vmcnt(0)" ::: "memory");
        if (kt < 15) __builtin_amdgcn_s_barrier();
    }

    // row sums: reduce per-lane partials over the 16 l15-lanes
#pragma unroll
    for (int r = 0; r < 4; r++) {
#pragma unroll
        for (int m = 1; m < 16; m <<= 1) plsum[r] += __shfl_xor(plsum[r], m, 16);
    }
    float inv[4];
#pragma unroll
    for (int r = 0; r < 4; r++) inv[r] = 1.0f / plsum[r];
#pragma unroll
    for (int ni = 0; ni < 8; ni++)
#pragma unroll
        for (int r = 0; r < 4; r++) {
            int qrow = q0 + w * 16 + q4 * 4 + r;
            ob[(size_t)g * 131072 + (size_t)qrow * 128 + ni * 16 + l15] =
                f2bf(o[ni][r] * inv[r]);
        }
}

// ---------------------------------------------------------------------------
extern "C" void kernel_launch(void* const* d_in, const int* in_sizes, int n_in,
                              void* d_out, int out_size, void* d_ws, size_t ws_size,
                              hipStream_t stream) {
    const float* x     = (const float*)d_in[0];
    const float* ln_g  = (const float*)d_in[1];
    const float* ln_b  = (const float*)d_in[2];
    const float* w_qkv = (const float*)d_in[3];
    const float* b_qkv = (const float*)d_in[4];
    const float* w_out = (const float*)d_in[5];
    const float* b_out = (const float*)d_in[6];
    float* out = (float*)d_out;

    const size_t MC = 8192ull * 1024ull;  // 8.39M elems
    ushort* xn    = (ushort*)d_ws;
    ushort* wqkvT = xn + MC;
    ushort* woutT = wqkvT + 3072ull * 1024ull;
    ushort* qbuf  = woutT + 1024ull * 1024ull;
    ushort* kbuf  = qbuf + MC;
    ushort* vtbuf = kbuf + MC;        // V^T [64 heads][128 d][1024 seq]
    ushort* attnb = vtbuf + MC;       // scratch for raw V, then attn output
    // total: 46.14M ushorts = 92.3 MB (same layout as passing rounds)

    prep_kernel<<<6144, 256, 0, stream>>>(x, ln_g, ln_b, xn, w_qkv, wqkvT, w_out, woutT);
    // q,k -> qbuf,kbuf ; v -> attnb (scratch, row-major coalesced)
    gemm_qkv<<<1536, 256, 0, stream>>>(xn, wqkvT, b_qkv, qbuf, kbuf, attnb);
    transpose_head<<<dim3(4, 32, 64), 256, 0, stream>>>(attnb, vtbuf);
    attn_kernel<<<1024, 256, 0, stream>>>(qbuf, kbuf, vtbuf, attnb);
    gemm_out<<<512, 256, 0, stream>>>(attnb, woutT, b_out, xn, out);
}

// Round 11
// 237.064 us; speedup vs baseline: 1.0789x; 1.0146x over previous
//
#include <hip/hip_runtime.h>
#include <hip/hip_bf16.h>

// ---------------------------------------------------------------------------
// AttentionBlock: B=8, L=1024, C=1024, H=8, ch=128.
// fp32 I/O, bf16 MFMA internal.
// R8: scattered 2B global stores amplify HBM writes ~10x.
// R13/R14: XCD band swizzle -> 49MB fetch; 1-block/CU lockstep caps util.
// R15: 128x128 tile 2-deep counted-vmcnt pipeline = 878 TF structure ceiling.
// R16: partial phase-schedule port regressed.  R20: scalar ds-scatter V
//      transpose in attn = too slow.  R21: QBLK=64 attn neutral (62.4us).
// R22: transpose_head ELIMINATED via W layout [g][d][s7][off] for V:
//      raw reshape algebra (g=rowBase>>7 fixed/tile, s7=(colBase-2048)>>7
//      fixed/tile, s=off*8+s7) means gemm_qkv V-epilogue writes W with
//      PACKED 8B stores (4 consecutive off), and attn stages V with the
//      same 16B gload_lds16 chunks (keys permuted within 64-key tile:
//      chunk c holds keys {8j+c}).  P stored at slot (key&7)*8+(key>>3)
//      keeps P/V k-indexing consistent; QK^T/plsum/PV/output untouched.
// ---------------------------------------------------------------------------

typedef __attribute__((ext_vector_type(8))) short short8;
typedef __attribute__((ext_vector_type(4))) float f32x4;

#define QK_SCALE 0.29730177875068026f  // 128^-0.25

__device__ __forceinline__ float bf2f(ushort u) {
    union { float f; unsigned int i; } c; c.i = ((unsigned int)u) << 16; return c.f;
}
__device__ __forceinline__ ushort f2bf(float f) {
    union { float f; unsigned int i; } c; c.f = f;
    unsigned int x = c.i;
    return (ushort)((x + 0x7FFFu + ((x >> 16) & 1u)) >> 16);  // RNE
}

// async 16B global->LDS (m97; LDS dest must be wave-uniform base + lane*16)
__device__ __forceinline__ void gload_lds16(const ushort* g, ushort* l) {
    __builtin_amdgcn_global_load_lds(
        (const __attribute__((address_space(1))) unsigned int*)g,
        (__attribute__((address_space(3))) unsigned int*)l, 16, 0, 0);
}

// ---------------------------------------------------------------------------
// Prep kernel: LN row-per-wave (blocks 0..2047, 4 rows/block, no barriers)
// + w_qkv transpose tiles (2048..5119) + w_out transpose (5120..6143).
// ---------------------------------------------------------------------------
__global__ __launch_bounds__(256) void prep_kernel(
    const float* __restrict__ x, const float* __restrict__ g,
    const float* __restrict__ b, ushort* __restrict__ xn,
    const float* __restrict__ w_qkv, ushort* __restrict__ wqkvT,
    const float* __restrict__ w_out, ushort* __restrict__ woutT) {
    __shared__ ushort t[32][33];
    int bid = blockIdx.x;
    int tid = threadIdx.x;
    if (bid < 2048) {
        // ---- LayerNorm: one row per wave ----
        int w = tid >> 6, lane = tid & 63;
        int row = bid * 4 + w;
        const float* xr = x + (size_t)row * 1024;
        float v[4][4];
        float s1 = 0.f, s2 = 0.f;
#pragma unroll
        for (int j = 0; j < 4; j++) {
            float4 t4 = *(const float4*)(xr + lane * 4 + j * 256);
            v[j][0] = t4.x; v[j][1] = t4.y; v[j][2] = t4.z; v[j][3] = t4.w;
#pragma unroll
            for (int e = 0; e < 4; e++) { s1 += v[j][e]; s2 += v[j][e] * v[j][e]; }
        }
#pragma unroll
        for (int m = 32; m >= 1; m >>= 1) { s1 += __shfl_xor(s1, m); s2 += __shfl_xor(s2, m); }
        float mu = s1 * (1.0f / 1024.0f);
        float var = s2 * (1.0f / 1024.0f) - mu * mu;
        float rs = rsqrtf(var + 1e-5f);
#pragma unroll
        for (int j = 0; j < 4; j++) {
            int c0 = lane * 4 + j * 256;
            float4 gg = *(const float4*)(g + c0);
            float4 bb = *(const float4*)(b + c0);
            float gA[4] = {gg.x, gg.y, gg.z, gg.w};
            float bA[4] = {bb.x, bb.y, bb.z, bb.w};
            ushort o[4];
#pragma unroll
            for (int e = 0; e < 4; e++) o[e] = f2bf((v[j][e] - mu) * rs * gA[e] + bA[e]);
            uint2 pk;
            pk.x = (uint)o[0] | ((uint)o[1] << 16);
            pk.y = (uint)o[2] | ((uint)o[3] << 16);
            *(uint2*)(xn + (size_t)row * 1024 + c0) = pk;
        }
    } else {
        // ---- weight transpose tile ----
        const float* in; ushort* out; int R, Cc, bx, by;
        if (bid < 5120) {
            int tt = bid - 2048;
            in = w_qkv; out = wqkvT; R = 1024; Cc = 3072;
            bx = (tt % 96) * 32; by = (tt / 96) * 32;
        } else {
            int tt = bid - 5120;
            in = w_out; out = woutT; R = 1024; Cc = 1024;
            bx = (tt % 32) * 32; by = (tt / 32) * 32;
        }
        int tx = tid & 31, ty = tid >> 5;
#pragma unroll
        for (int j = 0; j < 32; j += 8)
            t[ty + j][tx] = f2bf(in[(size_t)(by + ty + j) * Cc + bx + tx]);
        __syncthreads();
#pragma unroll
        for (int j = 0; j < 32; j += 8)
            out[(size_t)(bx + ty + j) * R + by + tx] = t[tx][ty + j];
    }
}

// ---------------------------------------------------------------------------
// QKV GEMM R22: C[8192,3072] = A[8192,1024] @ Bt[3072,1024]^T.
// 128x128 tile, BK=64, 256 thr = 4 waves.  LDS 64 KB -> 2 blocks/CU.
// 2-deep counted-vmcnt pipeline, vmcnt(8).  XOR-8 swizzle (conflict-free).
// Grid 1536 = 2/CU x 3 waves.  XCD x owns M-tiles [8x,8x+8), N-fastest.
// Q,K epilogue: scaled row-major bf16 (unchanged).
// V epilogue: writes W[g][d][s7][off] with 8B packed stores (g=rowBase>>7,
// s7=(colBase-2048)>>7, d=wcN+ni*16+l15, off=wrM+mi*16+q4*4+r).
// ---------------------------------------------------------------------------
__device__ __forceinline__ void stage8(const ushort* __restrict__ Ab,
                                       const ushort* __restrict__ Bb, int t2,
                                       ushort* AsD, ushort* BsD, int tid) {
    const ushort* As_src = Ab + t2 * 64;
    const ushort* Bs_src = Bb + t2 * 64;
#pragma unroll
    for (int i = 0; i < 4; i++) {
        int lin = i * 256 + tid;             // 0..1023: 16B chunk id of A tile
        int r = lin >> 3, p = lin & 7;
        int l = p ^ (r & 7);                 // logical chunk at phys slot p
        gload_lds16(As_src + (size_t)r * 1024 + l * 8, &AsD[lin * 8]);
    }
#pragma unroll
    for (int i = 0; i < 4; i++) {
        int lin = i * 256 + tid;             // 0..1023: chunk id of B tile
        int r = lin >> 3, p = lin & 7;
        int l = p ^ (r & 7);
        gload_lds16(Bs_src + (size_t)r * 1024 + l * 8, &BsD[lin * 8]);
    }
}

__global__ __launch_bounds__(256, 2) void gemm_qkv(
    const ushort* __restrict__ A, const ushort* __restrict__ Bt,
    const float* __restrict__ bias, ushort* __restrict__ out0,
    ushort* __restrict__ out1, ushort* __restrict__ wv) {
    __shared__ __align__(16) ushort As[2][128 * 64];  // 32 KB
    __shared__ __align__(16) ushort Bs[2][128 * 64];  // 32 KB

    int tid = threadIdx.x;
    int lane = tid & 63, w = tid >> 6;       // 4 waves
    int l15 = lane & 15, q4 = lane >> 4;
    int wrM = (w >> 1) * 64;                 // wave M offset: 0/64
    int wcN = (w & 1) * 64;                  // wave N offset: 0/64

    int bid = blockIdx.x;
    int xcd = bid & 7;
    int i = bid >> 3;                        // 0..191
    int by = xcd * 8 + (i & 7);              // M-tile 0..63
    int bx = i >> 3;                         // N-tile 0..23
    int rowBase = by * 128, colBase = bx * 128;

    const ushort* Ab = A + (size_t)rowBase * 1024;
    const ushort* Bb = Bt + (size_t)colBase * 1024;

    f32x4 acc[4][4];
    f32x4 zero = {0.f, 0.f, 0.f, 0.f};
#pragma unroll
    for (int mi = 0; mi < 4; mi++)
#pragma unroll
        for (int ni = 0; ni < 4; ni++) acc[mi][ni] = zero;

    // prologue: fill both buffers, wait only for buf0 (K1 stays in flight)
    stage8(Ab, Bb, 0, &As[0][0], &Bs[0][0], tid);
    stage8(Ab, Bb, 1, &As[1][0], &Bs[1][0], tid);
    asm volatile("s_waitcnt vmcnt(8)" ::: "memory");
    __builtin_amdgcn_s_barrier();

    for (int t = 0; t < 16; ++t) {
        const int cur = t & 1;
        const ushort* Ac = &As[cur][0];
        const ushort* Bc = &Bs[cur][0];

        // ---- read all 16 fragments of this K-tile into registers ----
        short8 aF[4][2], bF[4][2];
#pragma unroll
        for (int kk = 0; kk < 2; kk++) {
#pragma unroll
            for (int mi = 0; mi < 4; mi++) {
                int r = wrM + mi * 16 + l15;
                aF[mi][kk] = *(const short8*)&Ac[r * 64 + ((kk * 4 + q4) ^ (r & 7)) * 8];
            }
#pragma unroll
            for (int ni = 0; ni < 4; ni++) {
                int r = wcN + ni * 16 + l15;
                bF[ni][kk] = *(const short8*)&Bc[r * 64 + ((kk * 4 + q4) ^ (r & 7)) * 8];
            }
        }

        // ---- MFMA kk=0 ----
        __builtin_amdgcn_s_setprio(1);
#pragma unroll
        for (int mi = 0; mi < 4; mi++)
#pragma unroll
            for (int ni = 0; ni < 4; ni++)
                acc[mi][ni] = __builtin_amdgcn_mfma_f32_16x16x32_bf16(
                    aF[mi][0], bF[ni][0], acc[mi][ni], 0, 0, 0);
        __builtin_amdgcn_s_setprio(0);

        // all 16 reads sampled -> buf[cur] free for restaging (block-wide)
        asm volatile("s_waitcnt lgkmcnt(0)" ::: "memory");
        __builtin_amdgcn_s_barrier();
        if (t < 14) stage8(Ab, Bb, t + 2, &As[cur][0], &Bs[cur][0], tid);

        // ---- MFMA kk=1 (hides the stage issue + in-flight loads) ----
        __builtin_amdgcn_s_setprio(1);
#pragma unroll
        for (int mi = 0; mi < 4; mi++)
#pragma unroll
            for (int ni = 0; ni < 4; ni++)
                acc[mi][ni] = __builtin_amdgcn_mfma_f32_16x16x32_bf16(
                    aF[mi][1], bF[ni][1], acc[mi][ni], 0, 0, 0);
        __builtin_amdgcn_s_setprio(0);

        if (t < 15) {
            if (t < 14) asm volatile("s_waitcnt vmcnt(8)" ::: "memory");
            else        asm volatile("s_waitcnt vmcnt(0)" ::: "memory");
            __builtin_amdgcn_s_barrier();
        }
    }

    // C layout: col = lane&15, row = (lane>>4)*4 + r  [m89/m91]
    if (colBase < 2048) {
        // ---- Q/K epilogue: scaled row-major (unchanged) ----
#pragma unroll
        for (int ni = 0; ni < 4; ni++) {
            int col = colBase + wcN + ni * 16 + l15;
            float bv = bias[col];
            int cc = col & 1023;
            ushort* dst = (col < 1024) ? out0 : out1;
#pragma unroll
            for (int mi = 0; mi < 4; mi++) {
                f32x4 a = acc[mi][ni];
#pragma unroll
                for (int r = 0; r < 4; r++) {
                    int row = rowBase + wrM + mi * 16 + q4 * 4 + r;
                    dst[(size_t)row * 1024 + cc] = f2bf((a[r] + bv) * QK_SCALE);
                }
            }
        }
    } else {
        // ---- V epilogue: W[g][d][s7][off], packed 8B stores ----
        int g = rowBase >> 7;                 // = by (verified algebra)
        int s7 = (colBase - 2048) >> 7;       // 0..7
        ushort* Wg = wv + (size_t)g * 131072 + (size_t)s7 * 128;
#pragma unroll
        for (int ni = 0; ni < 4; ni++) {
            int col = colBase + wcN + ni * 16 + l15;
            float bv = bias[col];
            int d = wcN + ni * 16 + l15;      // 0..127
#pragma unroll
            for (int mi = 0; mi < 4; mi++) {
                f32x4 a = acc[mi][ni];
                int off0 = wrM + mi * 16 + q4 * 4;
                ushort o0 = f2bf(a[0] + bv), o1 = f2bf(a[1] + bv);
                ushort o2 = f2bf(a[2] + bv), o3 = f2bf(a[3] + bv);
                uint2 pk;
                pk.x = (uint)o0 | ((uint)o1 << 16);
                pk.y = (uint)o2 | ((uint)o3 << 16);
                *(uint2*)&Wg[(size_t)d * 1024 + off0] = pk;
            }
        }
    }
}

// ---------------------------------------------------------------------------
// Out-proj GEMM R18: outf[8192,1024] = A @ woutT^T + bias + resid (fp32 out).
// R15 2-deep structure: 128x128 tile, 256 thr, 64KB LDS, vmcnt(8) pipeline.
// Grid 512 = exactly 2/CU.  XCD x owns M-tiles [8x,8x+8), N-fastest.
// ---------------------------------------------------------------------------
__global__ __launch_bounds__(256, 2) void gemm_out(
    const ushort* __restrict__ A, const ushort* __restrict__ Bt,
    const float* __restrict__ bias, const ushort* __restrict__ resid,
    float* __restrict__ outf) {
    __shared__ __align__(16) ushort As[2][128 * 64];  // 32 KB
    __shared__ __align__(16) ushort Bs[2][128 * 64];  // 32 KB

    int tid = threadIdx.x;
    int lane = tid & 63, w = tid >> 6;       // 4 waves
    int l15 = lane & 15, q4 = lane >> 4;
    int wrM = (w >> 1) * 64;
    int wcN = (w & 1) * 64;

    int bid = blockIdx.x;
    int xcd = bid & 7;
    int i = bid >> 3;                        // 0..63
    int by = xcd * 8 + (i & 7);              // M-tile 0..63
    int bx = i >> 3;                         // N-tile 0..7
    int rowBase = by * 128, colBase = bx * 128;

    const ushort* Ab = A + (size_t)rowBase * 1024;
    const ushort* Bb = Bt + (size_t)colBase * 1024;

    f32x4 acc[4][4];
    f32x4 zero = {0.f, 0.f, 0.f, 0.f};
#pragma unroll
    for (int mi = 0; mi < 4; mi++)
#pragma unroll
        for (int ni = 0; ni < 4; ni++) acc[mi][ni] = zero;

    stage8(Ab, Bb, 0, &As[0][0], &Bs[0][0], tid);
    stage8(Ab, Bb, 1, &As[1][0], &Bs[1][0], tid);
    asm volatile("s_waitcnt vmcnt(8)" ::: "memory");
    __builtin_amdgcn_s_barrier();

    for (int t = 0; t < 16; ++t) {
        const int cur = t & 1;
        const ushort* Ac = &As[cur][0];
        const ushort* Bc = &Bs[cur][0];

        short8 aF[4][2], bF[4][2];
#pragma unroll
        for (int kk = 0; kk < 2; kk++) {
#pragma unroll
            for (int mi = 0; mi < 4; mi++) {
                int r = wrM + mi * 16 + l15;
                aF[mi][kk] = *(const short8*)&Ac[r * 64 + ((kk * 4 + q4) ^ (r & 7)) * 8];
            }
#pragma unroll
            for (int ni = 0; ni < 4; ni++) {
                int r = wcN + ni * 16 + l15;
                bF[ni][kk] = *(const short8*)&Bc[r * 64 + ((kk * 4 + q4) ^ (r & 7)) * 8];
            }
        }

        __builtin_amdgcn_s_setprio(1);
#pragma unroll
        for (int mi = 0; mi < 4; mi++)
#pragma unroll
            for (int ni = 0; ni < 4; ni++)
                acc[mi][ni] = __builtin_amdgcn_mfma_f32_16x16x32_bf16(
                    aF[mi][0], bF[ni][0], acc[mi][ni], 0, 0, 0);
        __builtin_amdgcn_s_setprio(0);

        asm volatile("s_waitcnt lgkmcnt(0)" ::: "memory");
        __builtin_amdgcn_s_barrier();
        if (t < 14) stage8(Ab, Bb, t + 2, &As[cur][0], &Bs[cur][0], tid);

        __builtin_amdgcn_s_setprio(1);
#pragma unroll
        for (int mi = 0; mi < 4; mi++)
#pragma unroll
            for (int ni = 0; ni < 4; ni++)
                acc[mi][ni] = __builtin_amdgcn_mfma_f32_16x16x32_bf16(
                    aF[mi][1], bF[ni][1], acc[mi][ni], 0, 0, 0);
        __builtin_amdgcn_s_setprio(0);

        if (t < 15) {
            if (t < 14) asm volatile("s_waitcnt vmcnt(8)" ::: "memory");
            else        asm volatile("s_waitcnt vmcnt(0)" ::: "memory");
            __builtin_amdgcn_s_barrier();
        }
    }

#pragma unroll
    for (int ni = 0; ni < 4; ni++) {
        int col = colBase + wcN + ni * 16 + l15;
        float bv = bias[col];
#pragma unroll
        for (int mi = 0; mi < 4; mi++) {
            f32x4 a = acc[mi][ni];
#pragma unroll
            for (int r = 0; r < 4; r++) {
                int row = rowBase + wrM + mi * 16 + q4 * 4 + r;
                outf[(size_t)row * 1024 + col] =
                    a[r] + bv + bf2f(resid[(size_t)row * 1024 + col]);
            }
        }
    }
}

// ---------------------------------------------------------------------------
// Attention R22: one block = (head g, 128 q-rows); 8 waves x 16q; 512 thr.
// LDS 80 KB: Ks[2] + Vt[2] dbuf + Ps.  2-deep counted-vmcnt (R19 proven).
// V staged from W[g][d][s7][off]: chunk (d, c=s7) at off kt*8 holds keys
// {8j+c} of tile kt -> P stored at slot (key&7)*8+(key>>3) so P/V k-index
// agree.  QK^T, plsum, PV reads, output all unchanged.
// XCD head-grouping: XCD x owns heads 8x..8x+7.
// ---------------------------------------------------------------------------
__device__ __forceinline__ void attn_stage(const ushort* __restrict__ Kh,
                                           const ushort* __restrict__ Wg,
                                           int kt, ushort* KsD, ushort* VtD,
                                           int tid) {
#pragma unroll
    for (int i = 0; i < 2; i++) {
        int linear = i * 512 + tid;          // 0..1023, wave-contiguous
        int r = linear >> 4, p = linear & 15;
        int l = p ^ (r & 15);
        gload_lds16(&Kh[(size_t)(kt * 64 + r) * 128 + l * 8], &KsD[linear * 8]);
    }
#pragma unroll
    for (int i = 0; i < 2; i++) {
        int linear = i * 512 + tid;          // 0..1023
        int d = linear >> 3, p = linear & 7;
        int c = p ^ (d & 7);                 // logical chunk = s7
        gload_lds16(&Wg[(size_t)d * 1024 + c * 128 + kt * 8], &VtD[linear * 8]);
    }
}

__global__ __launch_bounds__(512) void attn_kernel(
    const ushort* __restrict__ qb, const ushort* __restrict__ kb,
    const ushort* __restrict__ wv, ushort* __restrict__ ob) {
    // XCD head-grouping: XCD x (bid&7) owns heads 8x..8x+7, all 8 q-blocks.
    int bid = blockIdx.x;
    int xcd = bid & 7, ii = bid >> 3;        // ii 0..63
    int g = xcd * 8 + (ii >> 3);             // head 0..63
    int qblk = ii & 7;                       // 128-row q block
    const ushort* Qh = qb + (size_t)g * 131072;
    const ushort* Kh = kb + (size_t)g * 131072;
    const ushort* Wg = wv + (size_t)g * 131072;  // [128 d][8 s7][128 off]

    __shared__ __align__(16) ushort Ks[2][64 * 128];   // 32 KB
    __shared__ __align__(16) ushort Vt[2][128 * 64];   // 32 KB
    __shared__ __align__(16) ushort Ps[128 * 64];      // 16 KB

    int tid = threadIdx.x, lane = tid & 63, w = tid >> 6;  // w in [0,8)
    int l15 = lane & 15, q4 = lane >> 4;
    int q0 = qblk * 128;

    // Q A-fragments: A[m=l15][k = ks*32 + q4*8 + j]
    short8 qf[4];
#pragma unroll
    for (int ks = 0; ks < 4; ks++)
        qf[ks] = *(const short8*)&Qh[(size_t)(q0 + w * 16 + l15) * 128 + ks * 32 + q4 * 8];

    f32x4 zero = {0.f, 0.f, 0.f, 0.f};
    f32x4 o[8];
#pragma unroll
    for (int ni = 0; ni < 8; ni++) o[ni] = zero;
    float plsum[4] = {0.f, 0.f, 0.f, 0.f};

    // prologue: stage kt0 -> buf0, kt1 -> buf1; wait only kt0 (4 left)
    attn_stage(Kh, Wg, 0, &Ks[0][0], &Vt[0][0], tid);
    attn_stage(Kh, Wg, 1, &Ks[1][0], &Vt[1][0], tid);
    asm volatile("s_waitcnt vmcnt(4)" ::: "memory");
    __builtin_amdgcn_s_barrier();

    for (int kt = 0; kt < 16; kt++) {
        const int cur = kt & 1;
        const ushort* Kc = &Ks[cur][0];
        const ushort* Vc = &Vt[cur][0];

        // S = Q K^T : 16q x 64key per wave
        f32x4 sacc[4];
#pragma unroll
        for (int ni = 0; ni < 4; ni++) sacc[ni] = zero;
        __builtin_amdgcn_s_setprio(1);
#pragma unroll
        for (int ks = 0; ks < 4; ks++) {
#pragma unroll
            for (int ni = 0; ni < 4; ni++) {
                int r = ni * 16 + l15;
                int p = (ks * 4 + q4) ^ (r & 15);
                short8 bF = *(const short8*)&Kc[r * 128 + p * 8];
                sacc[ni] = __builtin_amdgcn_mfma_f32_16x16x32_bf16(
                    qf[ks], bF, sacc[ni], 0, 0, 0);
            }
        }
        __builtin_amdgcn_s_setprio(0);

        // P = exp(S) -> Ps at slot (key&7)*8+(key>>3) (W chunk semantics)
#pragma unroll
        for (int ni = 0; ni < 4; ni++) {
#pragma unroll
            for (int r = 0; r < 4; r++) {
                float pv = __expf(sacc[ni][r]);
                plsum[r] += pv;
                int qloc = w * 16 + q4 * 4 + r;       // wave-private rows
                int key = ni * 16 + l15;
                int pc = (key & 7) ^ (qloc & 7);      // slot chunk ^ swizzle
                Ps[qloc * 64 + pc * 8 + (key >> 3)] = f2bf(pv);
            }
        }

        // O += P V  (wave-private Ps rows; same-wave RAW handled by waitcnt)
        __builtin_amdgcn_s_setprio(1);
#pragma unroll
        for (int ks2 = 0; ks2 < 2; ks2++) {
            int c = ks2 * 4 + q4;
            int row = w * 16 + l15;                   // row&7 == l15&7
            short8 aF = *(const short8*)&Ps[row * 64 + (c ^ (l15 & 7)) * 8];
#pragma unroll
            for (int ni = 0; ni < 8; ni++) {
                int d = ni * 16 + l15;
                short8 bF = *(const short8*)&Vc[d * 64 + (c ^ (d & 7)) * 8];
                o[ni] = __builtin_amdgcn_mfma_f32_16x16x32_bf16(aF, bF, o[ni], 0, 0, 0);
            }
        }
        __builtin_amdgcn_s_setprio(0);

        // ---- all LDS reads of buf[cur] done -> restage; counted vmcnt ----
        asm volatile("s_waitcnt lgkmcnt(0)" ::: "memory");
        __builtin_amdgcn_s_barrier();
        if (kt < 14) attn_stage(Kh, Wg, kt + 2, &Ks[cur][0], &Vt[cur][0], tid);
        if (kt < 14)       asm volatile("s_waitcnt vmcnt(4)" ::: "memory");
        else if (kt == 14) asm volatile("s_waitcnt vmcnt(0)" ::: "memory");
        if (kt < 15) __builtin_amdgcn_s_barrier();
    }

    // row sums: reduce per-lane partials over the 16 l15-lanes
#pragma unroll
    for (int r = 0; r < 4; r++) {
#pragma unroll
        for (int m = 1; m < 16; m <<= 1) plsum[r] += __shfl_xor(plsum[r], m, 16);
    }
    float inv[4];
#pragma unroll
    for (int r = 0; r < 4; r++) inv[r] = 1.0f / plsum[r];
#pragma unroll
    for (int ni = 0; ni < 8; ni++)
#pragma unroll
        for (int r = 0; r < 4; r++) {
            int qrow = q0 + w * 16 + q4 * 4 + r;
            ob[(size_t)g * 131072 + (size_t)qrow * 128 + ni * 16 + l15] =
                f2bf(o[ni][r] * inv[r]);
        }
}

// ---------------------------------------------------------------------------
extern "C" void kernel_launch(void* const* d_in, const int* in_sizes, int n_in,
                              void* d_out, int out_size, void* d_ws, size_t ws_size,
                              hipStream_t stream) {
    const float* x     = (const float*)d_in[0];
    const float* ln_g  = (const float*)d_in[1];
    const float* ln_b  = (const float*)d_in[2];
    const float* w_qkv = (const float*)d_in[3];
    const float* b_qkv = (const float*)d_in[4];
    const float* w_out = (const float*)d_in[5];
    const float* b_out = (const float*)d_in[6];
    float* out = (float*)d_out;

    const size_t MC = 8192ull * 1024ull;  // 8.39M elems
    ushort* xn    = (ushort*)d_ws;
    ushort* wqkvT = xn + MC;
    ushort* woutT = wqkvT + 3072ull * 1024ull;
    ushort* qbuf  = woutT + 1024ull * 1024ull;
    ushort* kbuf  = qbuf + MC;
    ushort* vtbuf = kbuf + MC;        // W: V in [g][d][s7][off] layout
    ushort* attnb = vtbuf + MC;       // attn output
    // total: 46.14M ushorts = 92.3 MB (same layout as passing rounds)

    prep_kernel<<<6144, 256, 0, stream>>>(x, ln_g, ln_b, xn, w_qkv, wqkvT, w_out, woutT);
    // q,k -> qbuf,kbuf ; v -> vtbuf in W layout (transpose_head ELIMINATED)
    gemm_qkv<<<1536, 256, 0, stream>>>(xn, wqkvT, b_qkv, qbuf, kbuf, vtbuf);
    attn_kernel<<<512, 512, 0, stream>>>(qbuf, kbuf, vtbuf, attnb);
    gemm_out<<<512, 256, 0, stream>>>(attnb, woutT, b_out, xn, out);
}

// Round 13
// 232.194 us; speedup vs baseline: 1.1015x; 1.0210x over previous
//
#include <hip/hip_runtime.h>
#include <hip/hip_bf16.h>

// ---------------------------------------------------------------------------
// AttentionBlock: B=8, L=1024, C=1024, H=8, ch=128.
// fp32 I/O, bf16 MFMA internal.
// R8: scattered 2B global stores amplify HBM writes ~10x.
// R13/R14: XCD band swizzle -> 49MB fetch; 1-block/CU lockstep caps util.
// R15: 128x128 tile 2-deep counted-vmcnt pipeline = 878 TF structure ceiling.
// R16: partial phase-schedule port regressed.  R20: scalar ds-scatter V
//      transpose too slow.  R21: QBLK=64 attn neutral.
// R22: transpose_head ELIMINATED via W layout [g][d][s7][off] (237.1us best).
// R23: attn QBLK=256 -> 4 blocks/head, grid 256 = 1 block/CU.  Per-wave
//      q-rows 16->32 (two 16-row sub-blocks): staging + barriers per FLOP
//      halve; K/V fragments shared across sub-blocks.  attn_stage, swizzle,
//      vmcnt ledger, W semantics unchanged.
// R24: resubmit of R23 (container failed twice = infra flake, same as R1;
//      kernel re-audited: barriers uniform, bounds ok, VGPR ~200, LDS 96KB).
// ---------------------------------------------------------------------------

typedef __attribute__((ext_vector_type(8))) short short8;
typedef __attribute__((ext_vector_type(4))) float f32x4;

#define QK_SCALE 0.29730177875068026f  // 128^-0.25

__device__ __forceinline__ float bf2f(ushort u) {
    union { float f; unsigned int i; } c; c.i = ((unsigned int)u) << 16; return c.f;
}
__device__ __forceinline__ ushort f2bf(float f) {
    union { float f; unsigned int i; } c; c.f = f;
    unsigned int x = c.i;
    return (ushort)((x + 0x7FFFu + ((x >> 16) & 1u)) >> 16);  // RNE
}

// async 16B global->LDS (m97; LDS dest must be wave-uniform base + lane*16)
__device__ __forceinline__ void gload_lds16(const ushort* g, ushort* l) {
    __builtin_amdgcn_global_load_lds(
        (const __attribute__((address_space(1))) unsigned int*)g,
        (__attribute__((address_space(3))) unsigned int*)l, 16, 0, 0);
}

// ---------------------------------------------------------------------------
// Prep kernel: LN row-per-wave (blocks 0..2047, 4 rows/block, no barriers)
// + w_qkv transpose tiles (2048..5119) + w_out transpose (5120..6143).
// ---------------------------------------------------------------------------
__global__ __launch_bounds__(256) void prep_kernel(
    const float* __restrict__ x, const float* __restrict__ g,
    const float* __restrict__ b, ushort* __restrict__ xn,
    const float* __restrict__ w_qkv, ushort* __restrict__ wqkvT,
    const float* __restrict__ w_out, ushort* __restrict__ woutT) {
    __shared__ ushort t[32][33];
    int bid = blockIdx.x;
    int tid = threadIdx.x;
    if (bid < 2048) {
        // ---- LayerNorm: one row per wave ----
        int w = tid >> 6, lane = tid & 63;
        int row = bid * 4 + w;
        const float* xr = x + (size_t)row * 1024;
        float v[4][4];
        float s1 = 0.f, s2 = 0.f;
#pragma unroll
        for (int j = 0; j < 4; j++) {
            float4 t4 = *(const float4*)(xr + lane * 4 + j * 256);
            v[j][0] = t4.x; v[j][1] = t4.y; v[j][2] = t4.z; v[j][3] = t4.w;
#pragma unroll
            for (int e = 0; e < 4; e++) { s1 += v[j][e]; s2 += v[j][e] * v[j][e]; }
        }
#pragma unroll
        for (int m = 32; m >= 1; m >>= 1) { s1 += __shfl_xor(s1, m); s2 += __shfl_xor(s2, m); }
        float mu = s1 * (1.0f / 1024.0f);
        float var = s2 * (1.0f / 1024.0f) - mu * mu;
        float rs = rsqrtf(var + 1e-5f);
#pragma unroll
        for (int j = 0; j < 4; j++) {
            int c0 = lane * 4 + j * 256;
            float4 gg = *(const float4*)(g + c0);
            float4 bb = *(const float4*)(b + c0);
            float gA[4] = {gg.x, gg.y, gg.z, gg.w};
            float bA[4] = {bb.x, bb.y, bb.z, bb.w};
            ushort o[4];
#pragma unroll
            for (int e = 0; e < 4; e++) o[e] = f2bf((v[j][e] - mu) * rs * gA[e] + bA[e]);
            uint2 pk;
            pk.x = (uint)o[0] | ((uint)o[1] << 16);
            pk.y = (uint)o[2] | ((uint)o[3] << 16);
            *(uint2*)(xn + (size_t)row * 1024 + c0) = pk;
        }
    } else {
        // ---- weight transpose tile ----
        const float* in; ushort* out; int R, Cc, bx, by;
        if (bid < 5120) {
            int tt = bid - 2048;
            in = w_qkv; out = wqkvT; R = 1024; Cc = 3072;
            bx = (tt % 96) * 32; by = (tt / 96) * 32;
        } else {
            int tt = bid - 5120;
            in = w_out; out = woutT; R = 1024; Cc = 1024;
            bx = (tt % 32) * 32; by = (tt / 32) * 32;
        }
        int tx = tid & 31, ty = tid >> 5;
#pragma unroll
        for (int j = 0; j < 32; j += 8)
            t[ty + j][tx] = f2bf(in[(size_t)(by + ty + j) * Cc + bx + tx]);
        __syncthreads();
#pragma unroll
        for (int j = 0; j < 32; j += 8)
            out[(size_t)(bx + ty + j) * R + by + tx] = t[tx][ty + j];
    }
}

// ---------------------------------------------------------------------------
// QKV GEMM R22: C[8192,3072] = A[8192,1024] @ Bt[3072,1024]^T.
// 128x128 tile, BK=64, 256 thr = 4 waves.  LDS 64 KB -> 2 blocks/CU.
// 2-deep counted-vmcnt pipeline, vmcnt(8).  XOR-8 swizzle (conflict-free).
// Grid 1536 = 2/CU x 3 waves.  XCD x owns M-tiles [8x,8x+8), N-fastest.
// Q,K epilogue: scaled row-major bf16.  V epilogue: W[g][d][s7][off],
// packed 8B stores (g=rowBase>>7, s7=(colBase-2048)>>7).
// ---------------------------------------------------------------------------
__device__ __forceinline__ void stage8(const ushort* __restrict__ Ab,
                                       const ushort* __restrict__ Bb, int t2,
                                       ushort* AsD, ushort* BsD, int tid) {
    const ushort* As_src = Ab + t2 * 64;
    const ushort* Bs_src = Bb + t2 * 64;
#pragma unroll
    for (int i = 0; i < 4; i++) {
        int lin = i * 256 + tid;             // 0..1023: 16B chunk id of A tile
        int r = lin >> 3, p = lin & 7;
        int l = p ^ (r & 7);                 // logical chunk at phys slot p
        gload_lds16(As_src + (size_t)r * 1024 + l * 8, &AsD[lin * 8]);
    }
#pragma unroll
    for (int i = 0; i < 4; i++) {
        int lin = i * 256 + tid;             // 0..1023: chunk id of B tile
        int r = lin >> 3, p = lin & 7;
        int l = p ^ (r & 7);
        gload_lds16(Bs_src + (size_t)r * 1024 + l * 8, &BsD[lin * 8]);
    }
}

__global__ __launch_bounds__(256, 2) void gemm_qkv(
    const ushort* __restrict__ A, const ushort* __restrict__ Bt,
    const float* __restrict__ bias, ushort* __restrict__ out0,
    ushort* __restrict__ out1, ushort* __restrict__ wv) {
    __shared__ __align__(16) ushort As[2][128 * 64];  // 32 KB
    __shared__ __align__(16) ushort Bs[2][128 * 64];  // 32 KB

    int tid = threadIdx.x;
    int lane = tid & 63, w = tid >> 6;       // 4 waves
    int l15 = lane & 15, q4 = lane >> 4;
    int wrM = (w >> 1) * 64;                 // wave M offset: 0/64
    int wcN = (w & 1) * 64;                  // wave N offset: 0/64

    int bid = blockIdx.x;
    int xcd = bid & 7;
    int i = bid >> 3;                        // 0..191
    int by = xcd * 8 + (i & 7);              // M-tile 0..63
    int bx = i >> 3;                         // N-tile 0..23
    int rowBase = by * 128, colBase = bx * 128;

    const ushort* Ab = A + (size_t)rowBase * 1024;
    const ushort* Bb = Bt + (size_t)colBase * 1024;

    f32x4 acc[4][4];
    f32x4 zero = {0.f, 0.f, 0.f, 0.f};
#pragma unroll
    for (int mi = 0; mi < 4; mi++)
#pragma unroll
        for (int ni = 0; ni < 4; ni++) acc[mi][ni] = zero;

    // prologue: fill both buffers, wait only for buf0 (K1 stays in flight)
    stage8(Ab, Bb, 0, &As[0][0], &Bs[0][0], tid);
    stage8(Ab, Bb, 1, &As[1][0], &Bs[1][0], tid);
    asm volatile("s_waitcnt vmcnt(8)" ::: "memory");
    __builtin_amdgcn_s_barrier();

    for (int t = 0; t < 16; ++t) {
        const int cur = t & 1;
        const ushort* Ac = &As[cur][0];
        const ushort* Bc = &Bs[cur][0];

        // ---- read all 16 fragments of this K-tile into registers ----
        short8 aF[4][2], bF[4][2];
#pragma unroll
        for (int kk = 0; kk < 2; kk++) {
#pragma unroll
            for (int mi = 0; mi < 4; mi++) {
                int r = wrM + mi * 16 + l15;
                aF[mi][kk] = *(const short8*)&Ac[r * 64 + ((kk * 4 + q4) ^ (r & 7)) * 8];
            }
#pragma unroll
            for (int ni = 0; ni < 4; ni++) {
                int r = wcN + ni * 16 + l15;
                bF[ni][kk] = *(const short8*)&Bc[r * 64 + ((kk * 4 + q4) ^ (r & 7)) * 8];
            }
        }

        // ---- MFMA kk=0 ----
        __builtin_amdgcn_s_setprio(1);
#pragma unroll
        for (int mi = 0; mi < 4; mi++)
#pragma unroll
            for (int ni = 0; ni < 4; ni++)
                acc[mi][ni] = __builtin_amdgcn_mfma_f32_16x16x32_bf16(
                    aF[mi][0], bF[ni][0], acc[mi][ni], 0, 0, 0);
        __builtin_amdgcn_s_setprio(0);

        // all 16 reads sampled -> buf[cur] free for restaging (block-wide)
        asm volatile("s_waitcnt lgkmcnt(0)" ::: "memory");
        __builtin_amdgcn_s_barrier();
        if (t < 14) stage8(Ab, Bb, t + 2, &As[cur][0], &Bs[cur][0], tid);

        // ---- MFMA kk=1 (hides the stage issue + in-flight loads) ----
        __builtin_amdgcn_s_setprio(1);
#pragma unroll
        for (int mi = 0; mi < 4; mi++)
#pragma unroll
            for (int ni = 0; ni < 4; ni++)
                acc[mi][ni] = __builtin_amdgcn_mfma_f32_16x16x32_bf16(
                    aF[mi][1], bF[ni][1], acc[mi][ni], 0, 0, 0);
        __builtin_amdgcn_s_setprio(0);

        if (t < 15) {
            if (t < 14) asm volatile("s_waitcnt vmcnt(8)" ::: "memory");
            else        asm volatile("s_waitcnt vmcnt(0)" ::: "memory");
            __builtin_amdgcn_s_barrier();
        }
    }

    // C layout: col = lane&15, row = (lane>>4)*4 + r  [m89/m91]
    if (colBase < 2048) {
        // ---- Q/K epilogue: scaled row-major (unchanged) ----
#pragma unroll
        for (int ni = 0; ni < 4; ni++) {
            int col = colBase + wcN + ni * 16 + l15;
            float bv = bias[col];
            int cc = col & 1023;
            ushort* dst = (col < 1024) ? out0 : out1;
#pragma unroll
            for (int mi = 0; mi < 4; mi++) {
                f32x4 a = acc[mi][ni];
#pragma unroll
                for (int r = 0; r < 4; r++) {
                    int row = rowBase + wrM + mi * 16 + q4 * 4 + r;
                    dst[(size_t)row * 1024 + cc] = f2bf((a[r] + bv) * QK_SCALE);
                }
            }
        }
    } else {
        // ---- V epilogue: W[g][d][s7][off], packed 8B stores ----
        int g = rowBase >> 7;                 // = by (verified algebra)
        int s7 = (colBase - 2048) >> 7;       // 0..7
        ushort* Wg = wv + (size_t)g * 131072 + (size_t)s7 * 128;
#pragma unroll
        for (int ni = 0; ni < 4; ni++) {
            int col = colBase + wcN + ni * 16 + l15;
            float bv = bias[col];
            int d = wcN + ni * 16 + l15;      // 0..127
#pragma unroll
            for (int mi = 0; mi < 4; mi++) {
                f32x4 a = acc[mi][ni];
                int off0 = wrM + mi * 16 + q4 * 4;
                ushort o0 = f2bf(a[0] + bv), o1 = f2bf(a[1] + bv);
                ushort o2 = f2bf(a[2] + bv), o3 = f2bf(a[3] + bv);
                uint2 pk;
                pk.x = (uint)o0 | ((uint)o1 << 16);
                pk.y = (uint)o2 | ((uint)o3 << 16);
                *(uint2*)&Wg[(size_t)d * 1024 + off0] = pk;
            }
        }
    }
}

// ---------------------------------------------------------------------------
// Out-proj GEMM R18: outf[8192,1024] = A @ woutT^T + bias + resid (fp32 out).
// R15 2-deep structure: 128x128 tile, 256 thr, 64KB LDS, vmcnt(8) pipeline.
// Grid 512 = exactly 2/CU.  XCD x owns M-tiles [8x,8x+8), N-fastest.
// ---------------------------------------------------------------------------
__global__ __launch_bounds__(256, 2) void gemm_out(
    const ushort* __restrict__ A, const ushort* __restrict__ Bt,
    const float* __restrict__ bias, const ushort* __restrict__ resid,
    float* __restrict__ outf) {
    __shared__ __align__(16) ushort As[2][128 * 64];  // 32 KB
    __shared__ __align__(16) ushort Bs[2][128 * 64];  // 32 KB

    int tid = threadIdx.x;
    int lane = tid & 63, w = tid >> 6;       // 4 waves
    int l15 = lane & 15, q4 = lane >> 4;
    int wrM = (w >> 1) * 64;
    int wcN = (w & 1) * 64;

    int bid = blockIdx.x;
    int xcd = bid & 7;
    int i = bid >> 3;                        // 0..63
    int by = xcd * 8 + (i & 7);              // M-tile 0..63
    int bx = i >> 3;                         // N-tile 0..7
    int rowBase = by * 128, colBase = bx * 128;

    const ushort* Ab = A + (size_t)rowBase * 1024;
    const ushort* Bb = Bt + (size_t)colBase * 1024;

    f32x4 acc[4][4];
    f32x4 zero = {0.f, 0.f, 0.f, 0.f};
#pragma unroll
    for (int mi = 0; mi < 4; mi++)
#pragma unroll
        for (int ni = 0; ni < 4; ni++) acc[mi][ni] = zero;

    stage8(Ab, Bb, 0, &As[0][0], &Bs[0][0], tid);
    stage8(Ab, Bb, 1, &As[1][0], &Bs[1][0], tid);
    asm volatile("s_waitcnt vmcnt(8)" ::: "memory");
    __builtin_amdgcn_s_barrier();

    for (int t = 0; t < 16; ++t) {
        const int cur = t & 1;
        const ushort* Ac = &As[cur][0];
        const ushort* Bc = &Bs[cur][0];

        short8 aF[4][2], bF[4][2];
#pragma unroll
        for (int kk = 0; kk < 2; kk++) {
#pragma unroll
            for (int mi = 0; mi < 4; mi++) {
                int r = wrM + mi * 16 + l15;
                aF[mi][kk] = *(const short8*)&Ac[r * 64 + ((kk * 4 + q4) ^ (r & 7)) * 8];
            }
#pragma unroll
            for (int ni = 0; ni < 4; ni++) {
                int r = wcN + ni * 16 + l15;
                bF[ni][kk] = *(const short8*)&Bc[r * 64 + ((kk * 4 + q4) ^ (r & 7)) * 8];
            }
        }

        __builtin_amdgcn_s_setprio(1);
#pragma unroll
        for (int mi = 0; mi < 4; mi++)
#pragma unroll
            for (int ni = 0; ni < 4; ni++)
                acc[mi][ni] = __builtin_amdgcn_mfma_f32_16x16x32_bf16(
                    aF[mi][0], bF[ni][0], acc[mi][ni], 0, 0, 0);
        __builtin_amdgcn_s_setprio(0);

        asm volatile("s_waitcnt lgkmcnt(0)" ::: "memory");
        __builtin_amdgcn_s_barrier();
        if (t < 14) stage8(Ab, Bb, t + 2, &As[cur][0], &Bs[cur][0], tid);

        __builtin_amdgcn_s_setprio(1);
#pragma unroll
        for (int mi = 0; mi < 4; mi++)
#pragma unroll
            for (int ni = 0; ni < 4; ni++)
                acc[mi][ni] = __builtin_amdgcn_mfma_f32_16x16x32_bf16(
                    aF[mi][1], bF[ni][1], acc[mi][ni], 0, 0, 0);
        __builtin_amdgcn_s_setprio(0);

        if (t < 15) {
            if (t < 14) asm volatile("s_waitcnt vmcnt(8)" ::: "memory");
            else        asm volatile("s_waitcnt vmcnt(0)" ::: "memory");
            __builtin_amdgcn_s_barrier();
        }
    }

#pragma unroll
    for (int ni = 0; ni < 4; ni++) {
        int col = colBase + wcN + ni * 16 + l15;
        float bv = bias[col];
#pragma unroll
        for (int mi = 0; mi < 4; mi++) {
            f32x4 a = acc[mi][ni];
#pragma unroll
            for (int r = 0; r < 4; r++) {
                int row = rowBase + wrM + mi * 16 + q4 * 4 + r;
                outf[(size_t)row * 1024 + col] =
                    a[r] + bv + bf2f(resid[(size_t)row * 1024 + col]);
            }
        }
    }
}

// ---------------------------------------------------------------------------
// Attention R23: one block = (head g, 256 q-rows); 8 waves x 32q; 512 thr.
// Grid 256 = 1 block/CU, 4 blocks/head: staging + barriers per FLOP halve
// vs R22.  Each wave: two 16-row q sub-blocks; K/V fragments hoisted and
// shared across sub-blocks.  LDS 96 KB: Ks[2] 32K + Vt[2] 32K + Ps 32K.
// 2-deep counted-vmcnt pipeline (vmcnt(4) ledger), setprio, W-layout V.
// XCD head-grouping: XCD x owns heads 8x..8x+7 (4 q-blocks each).
// ---------------------------------------------------------------------------
__device__ __forceinline__ void attn_stage(const ushort* __restrict__ Kh,
                                           const ushort* __restrict__ Wg,
                                           int kt, ushort* KsD, ushort* VtD,
                                           int tid) {
#pragma unroll
    for (int i = 0; i < 2; i++) {
        int linear = i * 512 + tid;          // 0..1023, wave-contiguous
        int r = linear >> 4, p = linear & 15;
        int l = p ^ (r & 15);
        gload_lds16(&Kh[(size_t)(kt * 64 + r) * 128 + l * 8], &KsD[linear * 8]);
    }
#pragma unroll
    for (int i = 0; i < 2; i++) {
        int linear = i * 512 + tid;          // 0..1023
        int d = linear >> 3, p = linear & 7;
        int c = p ^ (d & 7);                 // logical chunk = s7
        gload_lds16(&Wg[(size_t)d * 1024 + c * 128 + kt * 8], &VtD[linear * 8]);
    }
}

__global__ __launch_bounds__(512) void attn_kernel(
    const ushort* __restrict__ qb, const ushort* __restrict__ kb,
    const ushort* __restrict__ wv, ushort* __restrict__ ob) {
    // XCD head-grouping: XCD x (bid&7) owns heads 8x..8x+7, 4 q-blocks each.
    int bid = blockIdx.x;
    int xcd = bid & 7, ii = bid >> 3;        // ii 0..31
    int g = xcd * 8 + (ii >> 2);             // head 0..63
    int qblk = ii & 3;                       // 256-row q block
    const ushort* Qh = qb + (size_t)g * 131072;
    const ushort* Kh = kb + (size_t)g * 131072;
    const ushort* Wg = wv + (size_t)g * 131072;  // [128 d][8 s7][128 off]

    __shared__ __align__(16) ushort Ks[2][64 * 128];   // 32 KB
    __shared__ __align__(16) ushort Vt[2][128 * 64];   // 32 KB
    __shared__ __align__(16) ushort Ps[256 * 64];      // 32 KB

    int tid = threadIdx.x, lane = tid & 63, w = tid >> 6;  // w in [0,8)
    int l15 = lane & 15, q4 = lane >> 4;
    int q0 = qblk * 256;

    // Q A-fragments for 2 sub-blocks: rows q0 + w*32 + sub*16 + l15
    short8 qf[2][4];
#pragma unroll
    for (int sub = 0; sub < 2; sub++)
#pragma unroll
        for (int ks = 0; ks < 4; ks++)
            qf[sub][ks] = *(const short8*)&Qh[
                (size_t)(q0 + w * 32 + sub * 16 + l15) * 128 + ks * 32 + q4 * 8];

    f32x4 zero = {0.f, 0.f, 0.f, 0.f};
    f32x4 o[2][8];
#pragma unroll
    for (int sub = 0; sub < 2; sub++)
#pragma unroll
        for (int ni = 0; ni < 8; ni++) o[sub][ni] = zero;
    float plsum[2][4] = {{0.f, 0.f, 0.f, 0.f}, {0.f, 0.f, 0.f, 0.f}};

    // prologue: stage kt0 -> buf0, kt1 -> buf1; wait only kt0 (4 left)
    attn_stage(Kh, Wg, 0, &Ks[0][0], &Vt[0][0], tid);
    attn_stage(Kh, Wg, 1, &Ks[1][0], &Vt[1][0], tid);
    asm volatile("s_waitcnt vmcnt(4)" ::: "memory");
    __builtin_amdgcn_s_barrier();

    for (int kt = 0; kt < 16; kt++) {
        const int cur = kt & 1;
        const ushort* Kc = &Ks[cur][0];
        const ushort* Vc = &Vt[cur][0];

        // S = Q K^T : 32q x 64key per wave; K frag shared across sub-blocks
        f32x4 sacc[2][4];
#pragma unroll
        for (int sub = 0; sub < 2; sub++)
#pragma unroll
            for (int ni = 0; ni < 4; ni++) sacc[sub][ni] = zero;
        __builtin_amdgcn_s_setprio(1);
#pragma unroll
        for (int ks = 0; ks < 4; ks++) {
#pragma unroll
            for (int ni = 0; ni < 4; ni++) {
                int r = ni * 16 + l15;
                int p = (ks * 4 + q4) ^ (r & 15);
                short8 bF = *(const short8*)&Kc[r * 128 + p * 8];
#pragma unroll
                for (int sub = 0; sub < 2; sub++)
                    sacc[sub][ni] = __builtin_amdgcn_mfma_f32_16x16x32_bf16(
                        qf[sub][ks], bF, sacc[sub][ni], 0, 0, 0);
            }
        }
        __builtin_amdgcn_s_setprio(0);

        // P = exp(S) -> Ps at slot (key&7)*8+(key>>3) (W chunk semantics)
#pragma unroll
        for (int sub = 0; sub < 2; sub++)
#pragma unroll
            for (int ni = 0; ni < 4; ni++) {
#pragma unroll
                for (int r = 0; r < 4; r++) {
                    float pv = __expf(sacc[sub][ni][r]);
                    plsum[sub][r] += pv;
                    int qloc = w * 32 + sub * 16 + q4 * 4 + r;  // wave-private
                    int key = ni * 16 + l15;
                    int pc = (key & 7) ^ (qloc & 7);
                    Ps[qloc * 64 + pc * 8 + (key >> 3)] = f2bf(pv);
                }
            }

        // O += P V  (V frag shared across sub-blocks)
        __builtin_amdgcn_s_setprio(1);
#pragma unroll
        for (int ks2 = 0; ks2 < 2; ks2++) {
            int c = ks2 * 4 + q4;
            short8 aF[2];
#pragma unroll
            for (int sub = 0; sub < 2; sub++) {
                int row = w * 32 + sub * 16 + l15;            // row&7 == l15&7
                aF[sub] = *(const short8*)&Ps[row * 64 + (c ^ (l15 & 7)) * 8];
            }
#pragma unroll
            for (int ni = 0; ni < 8; ni++) {
                int d = ni * 16 + l15;
                short8 bF = *(const short8*)&Vc[d * 64 + (c ^ (d & 7)) * 8];
#pragma unroll
                for (int sub = 0; sub < 2; sub++)
                    o[sub][ni] = __builtin_amdgcn_mfma_f32_16x16x32_bf16(
                        aF[sub], bF, o[sub][ni], 0, 0, 0);
            }
        }
        __builtin_amdgcn_s_setprio(0);

        // ---- all LDS reads of buf[cur] done -> restage; counted vmcnt ----
        asm volatile("s_waitcnt lgkmcnt(0)" ::: "memory");
        __builtin_amdgcn_s_barrier();
        if (kt < 14) attn_stage(Kh, Wg, kt + 2, &Ks[cur][0], &Vt[cur][0], tid);
        if (kt < 14)       asm volatile("s_waitcnt vmcnt(4)" ::: "memory");
        else if (kt == 14) asm volatile("s_waitcnt vmcnt(0)" ::: "memory");
        if (kt < 15) __builtin_amdgcn_s_barrier();
    }

    // row sums: reduce per-lane partials over the 16 l15-lanes
#pragma unroll
    for (int sub = 0; sub < 2; sub++)
#pragma unroll
        for (int r = 0; r < 4; r++) {
#pragma unroll
            for (int m = 1; m < 16; m <<= 1)
                plsum[sub][r] += __shfl_xor(plsum[sub][r], m, 16);
        }
#pragma unroll
    for (int sub = 0; sub < 2; sub++) {
        float inv[4];
#pragma unroll
        for (int r = 0; r < 4; r++) inv[r] = 1.0f / plsum[sub][r];
#pragma unroll
        for (int ni = 0; ni < 8; ni++)
#pragma unroll
            for (int r = 0; r < 4; r++) {
                int qrow = q0 + w * 32 + sub * 16 + q4 * 4 + r;
                ob[(size_t)g * 131072 + (size_t)qrow * 128 + ni * 16 + l15] =
                    f2bf(o[sub][ni][r] * inv[r]);
            }
    }
}

// ---------------------------------------------------------------------------
extern "C" void kernel_launch(void* const* d_in, const int* in_sizes, int n_in,
                              void* d_out, int out_size, void* d_ws, size_t ws_size,
                              hipStream_t stream) {
    const float* x     = (const float*)d_in[0];
    const float* ln_g  = (const float*)d_in[1];
    const float* ln_b  = (const float*)d_in[2];
    const float* w_qkv = (const float*)d_in[3];
    const float* b_qkv = (const float*)d_in[4];
    const float* w_out = (const float*)d_in[5];
    const float* b_out = (const float*)d_in[6];
    float* out = (float*)d_out;

    const size_t MC = 8192ull * 1024ull;  // 8.39M elems
    ushort* xn    = (ushort*)d_ws;
    ushort* wqkvT = xn + MC;
    ushort* woutT = wqkvT + 3072ull * 1024ull;
    ushort* qbuf  = woutT + 1024ull * 1024ull;
    ushort* kbuf  = qbuf + MC;
    ushort* vtbuf = kbuf + MC;        // W: V in [g][d][s7][off] layout
    ushort* attnb = vtbuf + MC;       // attn output
    // total: 46.14M ushorts = 92.3 MB (same layout as passing rounds)

    prep_kernel<<<6144, 256, 0, stream>>>(x, ln_g, ln_b, xn, w_qkv, wqkvT, w_out, woutT);
    // q,k -> qbuf,kbuf ; v -> vtbuf in W layout (transpose_head eliminated)
    gemm_qkv<<<1536, 256, 0, stream>>>(xn, wqkvT, b_qkv, qbuf, kbuf, vtbuf);
    attn_kernel<<<256, 512, 0, stream>>>(qbuf, kbuf, vtbuf, attnb);
    gemm_out<<<512, 256, 0, stream>>>(attnb, woutT, b_out, xn, out);
}

// Round 14
// 225.399 us; speedup vs baseline: 1.1347x; 1.0301x over previous
//
#include <hip/hip_runtime.h>
#include <hip/hip_bf16.h>

// ---------------------------------------------------------------------------
// AttentionBlock: B=8, L=1024, C=1024, H=8, ch=128.
// fp32 I/O, bf16 MFMA internal.
// R8: scattered 2B global stores amplify HBM writes ~10x.
// R13/R14: XCD band swizzle -> 49MB fetch; 1-block/CU lockstep caps util.
// R15: 128x128 tile 2-deep counted-vmcnt pipeline = 878 TF structure ceiling.
// R16: partial phase-schedule port regressed -- do not re-roll from prose.
// R20: scalar ds-scatter V transpose too slow.  R21: QBLK=64 neutral.
// R22: transpose_head ELIMINATED via W layout [g][d][s7][off] (237.1us).
// R23/24: attn QBLK=256 (1 block/CU, 4 blocks/head): 232.2us best.
// R25: attn KVBLK 64->128: staging iterations 16->8, barriers/vmcnt per
//      FLOP halve (same amortization as R23).  Iteration = two identical
//      proven 64-key halves (Ps reuse = same-wave in-order LDS dep, already
//      proven across iterations).  LDS 160KB exact: Ks[2][128x128] 64K +
//      Vt[2][128x128] 64K + Ps[256x64] 32K.  vmcnt(8) ledger (R19 shape).
// ---------------------------------------------------------------------------

typedef __attribute__((ext_vector_type(8))) short short8;
typedef __attribute__((ext_vector_type(4))) float f32x4;

#define QK_SCALE 0.29730177875068026f  // 128^-0.25

__device__ __forceinline__ float bf2f(ushort u) {
    union { float f; unsigned int i; } c; c.i = ((unsigned int)u) << 16; return c.f;
}
__device__ __forceinline__ ushort f2bf(float f) {
    union { float f; unsigned int i; } c; c.f = f;
    unsigned int x = c.i;
    return (ushort)((x + 0x7FFFu + ((x >> 16) & 1u)) >> 16);  // RNE
}

// async 16B global->LDS (m97; LDS dest must be wave-uniform base + lane*16)
__device__ __forceinline__ void gload_lds16(const ushort* g, ushort* l) {
    __builtin_amdgcn_global_load_lds(
        (const __attribute__((address_space(1))) unsigned int*)g,
        (__attribute__((address_space(3))) unsigned int*)l, 16, 0, 0);
}

// ---------------------------------------------------------------------------
// Prep kernel: LN row-per-wave (blocks 0..2047, 4 rows/block, no barriers)
// + w_qkv transpose tiles (2048..5119) + w_out transpose (5120..6143).
// ---------------------------------------------------------------------------
__global__ __launch_bounds__(256) void prep_kernel(
    const float* __restrict__ x, const float* __restrict__ g,
    const float* __restrict__ b, ushort* __restrict__ xn,
    const float* __restrict__ w_qkv, ushort* __restrict__ wqkvT,
    const float* __restrict__ w_out, ushort* __restrict__ woutT) {
    __shared__ ushort t[32][33];
    int bid = blockIdx.x;
    int tid = threadIdx.x;
    if (bid < 2048) {
        // ---- LayerNorm: one row per wave ----
        int w = tid >> 6, lane = tid & 63;
        int row = bid * 4 + w;
        const float* xr = x + (size_t)row * 1024;
        float v[4][4];
        float s1 = 0.f, s2 = 0.f;
#pragma unroll
        for (int j = 0; j < 4; j++) {
            float4 t4 = *(const float4*)(xr + lane * 4 + j * 256);
            v[j][0] = t4.x; v[j][1] = t4.y; v[j][2] = t4.z; v[j][3] = t4.w;
#pragma unroll
            for (int e = 0; e < 4; e++) { s1 += v[j][e]; s2 += v[j][e] * v[j][e]; }
        }
#pragma unroll
        for (int m = 32; m >= 1; m >>= 1) { s1 += __shfl_xor(s1, m); s2 += __shfl_xor(s2, m); }
        float mu = s1 * (1.0f / 1024.0f);
        float var = s2 * (1.0f / 1024.0f) - mu * mu;
        float rs = rsqrtf(var + 1e-5f);
#pragma unroll
        for (int j = 0; j < 4; j++) {
            int c0 = lane * 4 + j * 256;
            float4 gg = *(const float4*)(g + c0);
            float4 bb = *(const float4*)(b + c0);
            float gA[4] = {gg.x, gg.y, gg.z, gg.w};
            float bA[4] = {bb.x, bb.y, bb.z, bb.w};
            ushort o[4];
#pragma unroll
            for (int e = 0; e < 4; e++) o[e] = f2bf((v[j][e] - mu) * rs * gA[e] + bA[e]);
            uint2 pk;
            pk.x = (uint)o[0] | ((uint)o[1] << 16);
            pk.y = (uint)o[2] | ((uint)o[3] << 16);
            *(uint2*)(xn + (size_t)row * 1024 + c0) = pk;
        }
    } else {
        // ---- weight transpose tile ----
        const float* in; ushort* out; int R, Cc, bx, by;
        if (bid < 5120) {
            int tt = bid - 2048;
            in = w_qkv; out = wqkvT; R = 1024; Cc = 3072;
            bx = (tt % 96) * 32; by = (tt / 96) * 32;
        } else {
            int tt = bid - 5120;
            in = w_out; out = woutT; R = 1024; Cc = 1024;
            bx = (tt % 32) * 32; by = (tt / 32) * 32;
        }
        int tx = tid & 31, ty = tid >> 5;
#pragma unroll
        for (int j = 0; j < 32; j += 8)
            t[ty + j][tx] = f2bf(in[(size_t)(by + ty + j) * Cc + bx + tx]);
        __syncthreads();
#pragma unroll
        for (int j = 0; j < 32; j += 8)
            out[(size_t)(bx + ty + j) * R + by + tx] = t[tx][ty + j];
    }
}

// ---------------------------------------------------------------------------
// QKV GEMM R22: C[8192,3072] = A[8192,1024] @ Bt[3072,1024]^T.
// 128x128 tile, BK=64, 256 thr = 4 waves.  LDS 64 KB -> 2 blocks/CU.
// 2-deep counted-vmcnt pipeline, vmcnt(8).  XOR-8 swizzle (conflict-free).
// Grid 1536 = 2/CU x 3 waves.  XCD x owns M-tiles [8x,8x+8), N-fastest.
// Q,K epilogue: scaled row-major bf16.  V epilogue: W[g][d][s7][off],
// packed 8B stores (g=rowBase>>7, s7=(colBase-2048)>>7).
// ---------------------------------------------------------------------------
__device__ __forceinline__ void stage8(const ushort* __restrict__ Ab,
                                       const ushort* __restrict__ Bb, int t2,
                                       ushort* AsD, ushort* BsD, int tid) {
    const ushort* As_src = Ab + t2 * 64;
    const ushort* Bs_src = Bb + t2 * 64;
#pragma unroll
    for (int i = 0; i < 4; i++) {
        int lin = i * 256 + tid;             // 0..1023: 16B chunk id of A tile
        int r = lin >> 3, p = lin & 7;
        int l = p ^ (r & 7);                 // logical chunk at phys slot p
        gload_lds16(As_src + (size_t)r * 1024 + l * 8, &AsD[lin * 8]);
    }
#pragma unroll
    for (int i = 0; i < 4; i++) {
        int lin = i * 256 + tid;             // 0..1023: chunk id of B tile
        int r = lin >> 3, p = lin & 7;
        int l = p ^ (r & 7);
        gload_lds16(Bs_src + (size_t)r * 1024 + l * 8, &BsD[lin * 8]);
    }
}

__global__ __launch_bounds__(256, 2) void gemm_qkv(
    const ushort* __restrict__ A, const ushort* __restrict__ Bt,
    const float* __restrict__ bias, ushort* __restrict__ out0,
    ushort* __restrict__ out1, ushort* __restrict__ wv) {
    __shared__ __align__(16) ushort As[2][128 * 64];  // 32 KB
    __shared__ __align__(16) ushort Bs[2][128 * 64];  // 32 KB

    int tid = threadIdx.x;
    int lane = tid & 63, w = tid >> 6;       // 4 waves
    int l15 = lane & 15, q4 = lane >> 4;
    int wrM = (w >> 1) * 64;                 // wave M offset: 0/64
    int wcN = (w & 1) * 64;                  // wave N offset: 0/64

    int bid = blockIdx.x;
    int xcd = bid & 7;
    int i = bid >> 3;                        // 0..191
    int by = xcd * 8 + (i & 7);              // M-tile 0..63
    int bx = i >> 3;                         // N-tile 0..23
    int rowBase = by * 128, colBase = bx * 128;

    const ushort* Ab = A + (size_t)rowBase * 1024;
    const ushort* Bb = Bt + (size_t)colBase * 1024;

    f32x4 acc[4][4];
    f32x4 zero = {0.f, 0.f, 0.f, 0.f};
#pragma unroll
    for (int mi = 0; mi < 4; mi++)
#pragma unroll
        for (int ni = 0; ni < 4; ni++) acc[mi][ni] = zero;

    // prologue: fill both buffers, wait only for buf0 (K1 stays in flight)
    stage8(Ab, Bb, 0, &As[0][0], &Bs[0][0], tid);
    stage8(Ab, Bb, 1, &As[1][0], &Bs[1][0], tid);
    asm volatile("s_waitcnt vmcnt(8)" ::: "memory");
    __builtin_amdgcn_s_barrier();

    for (int t = 0; t < 16; ++t) {
        const int cur = t & 1;
        const ushort* Ac = &As[cur][0];
        const ushort* Bc = &Bs[cur][0];

        // ---- read all 16 fragments of this K-tile into registers ----
        short8 aF[4][2], bF[4][2];
#pragma unroll
        for (int kk = 0; kk < 2; kk++) {
#pragma unroll
            for (int mi = 0; mi < 4; mi++) {
                int r = wrM + mi * 16 + l15;
                aF[mi][kk] = *(const short8*)&Ac[r * 64 + ((kk * 4 + q4) ^ (r & 7)) * 8];
            }
#pragma unroll
            for (int ni = 0; ni < 4; ni++) {
                int r = wcN + ni * 16 + l15;
                bF[ni][kk] = *(const short8*)&Bc[r * 64 + ((kk * 4 + q4) ^ (r & 7)) * 8];
            }
        }

        // ---- MFMA kk=0 ----
        __builtin_amdgcn_s_setprio(1);
#pragma unroll
        for (int mi = 0; mi < 4; mi++)
#pragma unroll
            for (int ni = 0; ni < 4; ni++)
                acc[mi][ni] = __builtin_amdgcn_mfma_f32_16x16x32_bf16(
                    aF[mi][0], bF[ni][0], acc[mi][ni], 0, 0, 0);
        __builtin_amdgcn_s_setprio(0);

        // all 16 reads sampled -> buf[cur] free for restaging (block-wide)
        asm volatile("s_waitcnt lgkmcnt(0)" ::: "memory");
        __builtin_amdgcn_s_barrier();
        if (t < 14) stage8(Ab, Bb, t + 2, &As[cur][0], &Bs[cur][0], tid);

        // ---- MFMA kk=1 (hides the stage issue + in-flight loads) ----
        __builtin_amdgcn_s_setprio(1);
#pragma unroll
        for (int mi = 0; mi < 4; mi++)
#pragma unroll
            for (int ni = 0; ni < 4; ni++)
                acc[mi][ni] = __builtin_amdgcn_mfma_f32_16x16x32_bf16(
                    aF[mi][1], bF[ni][1], acc[mi][ni], 0, 0, 0);
        __builtin_amdgcn_s_setprio(0);

        if (t < 15) {
            if (t < 14) asm volatile("s_waitcnt vmcnt(8)" ::: "memory");
            else        asm volatile("s_waitcnt vmcnt(0)" ::: "memory");
            __builtin_amdgcn_s_barrier();
        }
    }

    // C layout: col = lane&15, row = (lane>>4)*4 + r  [m89/m91]
    if (colBase < 2048) {
        // ---- Q/K epilogue: scaled row-major (unchanged) ----
#pragma unroll
        for (int ni = 0; ni < 4; ni++) {
            int col = colBase + wcN + ni * 16 + l15;
            float bv = bias[col];
            int cc = col & 1023;
            ushort* dst = (col < 1024) ? out0 : out1;
#pragma unroll
            for (int mi = 0; mi < 4; mi++) {
                f32x4 a = acc[mi][ni];
#pragma unroll
                for (int r = 0; r < 4; r++) {
                    int row = rowBase + wrM + mi * 16 + q4 * 4 + r;
                    dst[(size_t)row * 1024 + cc] = f2bf((a[r] + bv) * QK_SCALE);
                }
            }
        }
    } else {
        // ---- V epilogue: W[g][d][s7][off], packed 8B stores ----
        int g = rowBase >> 7;                 // = by (verified algebra)
        int s7 = (colBase - 2048) >> 7;       // 0..7
        ushort* Wg = wv + (size_t)g * 131072 + (size_t)s7 * 128;
#pragma unroll
        for (int ni = 0; ni < 4; ni++) {
            int col = colBase + wcN + ni * 16 + l15;
            float bv = bias[col];
            int d = wcN + ni * 16 + l15;      // 0..127
#pragma unroll
            for (int mi = 0; mi < 4; mi++) {
                f32x4 a = acc[mi][ni];
                int off0 = wrM + mi * 16 + q4 * 4;
                ushort o0 = f2bf(a[0] + bv), o1 = f2bf(a[1] + bv);
                ushort o2 = f2bf(a[2] + bv), o3 = f2bf(a[3] + bv);
                uint2 pk;
                pk.x = (uint)o0 | ((uint)o1 << 16);
                pk.y = (uint)o2 | ((uint)o3 << 16);
                *(uint2*)&Wg[(size_t)d * 1024 + off0] = pk;
            }
        }
    }
}

// ---------------------------------------------------------------------------
// Out-proj GEMM R18: outf[8192,1024] = A @ woutT^T + bias + resid (fp32 out).
// R15 2-deep structure: 128x128 tile, 256 thr, 64KB LDS, vmcnt(8) pipeline.
// Grid 512 = exactly 2/CU.  XCD x owns M-tiles [8x,8x+8), N-fastest.
// ---------------------------------------------------------------------------
__global__ __launch_bounds__(256, 2) void gemm_out(
    const ushort* __restrict__ A, const ushort* __restrict__ Bt,
    const float* __restrict__ bias, const ushort* __restrict__ resid,
    float* __restrict__ outf) {
    __shared__ __align__(16) ushort As[2][128 * 64];  // 32 KB
    __shared__ __align__(16) ushort Bs[2][128 * 64];  // 32 KB

    int tid = threadIdx.x;
    int lane = tid & 63, w = tid >> 6;       // 4 waves
    int l15 = lane & 15, q4 = lane >> 4;
    int wrM = (w >> 1) * 64;
    int wcN = (w & 1) * 64;

    int bid = blockIdx.x;
    int xcd = bid & 7;
    int i = bid >> 3;                        // 0..63
    int by = xcd * 8 + (i & 7);              // M-tile 0..63
    int bx = i >> 3;                         // N-tile 0..7
    int rowBase = by * 128, colBase = bx * 128;

    const ushort* Ab = A + (size_t)rowBase * 1024;
    const ushort* Bb = Bt + (size_t)colBase * 1024;

    f32x4 acc[4][4];
    f32x4 zero = {0.f, 0.f, 0.f, 0.f};
#pragma unroll
    for (int mi = 0; mi < 4; mi++)
#pragma unroll
        for (int ni = 0; ni < 4; ni++) acc[mi][ni] = zero;

    stage8(Ab, Bb, 0, &As[0][0], &Bs[0][0], tid);
    stage8(Ab, Bb, 1, &As[1][0], &Bs[1][0], tid);
    asm volatile("s_waitcnt vmcnt(8)" ::: "memory");
    __builtin_amdgcn_s_barrier();

    for (int t = 0; t < 16; ++t) {
        const int cur = t & 1;
        const ushort* Ac = &As[cur][0];
        const ushort* Bc = &Bs[cur][0];

        short8 aF[4][2], bF[4][2];
#pragma unroll
        for (int kk = 0; kk < 2; kk++) {
#pragma unroll
            for (int mi = 0; mi < 4; mi++) {
                int r = wrM + mi * 16 + l15;
                aF[mi][kk] = *(const short8*)&Ac[r * 64 + ((kk * 4 + q4) ^ (r & 7)) * 8];
            }
#pragma unroll
            for (int ni = 0; ni < 4; ni++) {
                int r = wcN + ni * 16 + l15;
                bF[ni][kk] = *(const short8*)&Bc[r * 64 + ((kk * 4 + q4) ^ (r & 7)) * 8];
            }
        }

        __builtin_amdgcn_s_setprio(1);
#pragma unroll
        for (int mi = 0; mi < 4; mi++)
#pragma unroll
            for (int ni = 0; ni < 4; ni++)
                acc[mi][ni] = __builtin_amdgcn_mfma_f32_16x16x32_bf16(
                    aF[mi][0], bF[ni][0], acc[mi][ni], 0, 0, 0);
        __builtin_amdgcn_s_setprio(0);

        asm volatile("s_waitcnt lgkmcnt(0)" ::: "memory");
        __builtin_amdgcn_s_barrier();
        if (t < 14) stage8(Ab, Bb, t + 2, &As[cur][0], &Bs[cur][0], tid);

        __builtin_amdgcn_s_setprio(1);
#pragma unroll
        for (int mi = 0; mi < 4; mi++)
#pragma unroll
            for (int ni = 0; ni < 4; ni++)
                acc[mi][ni] = __builtin_amdgcn_mfma_f32_16x16x32_bf16(
                    aF[mi][1], bF[ni][1], acc[mi][ni], 0, 0, 0);
        __builtin_amdgcn_s_setprio(0);

        if (t < 15) {
            if (t < 14) asm volatile("s_waitcnt vmcnt(8)" ::: "memory");
            else        asm volatile("s_waitcnt vmcnt(0)" ::: "memory");
            __builtin_amdgcn_s_barrier();
        }
    }

#pragma unroll
    for (int ni = 0; ni < 4; ni++) {
        int col = colBase + wcN + ni * 16 + l15;
        float bv = bias[col];
#pragma unroll
        for (int mi = 0; mi < 4; mi++) {
            f32x4 a = acc[mi][ni];
#pragma unroll
            for (int r = 0; r < 4; r++) {
                int row = rowBase + wrM + mi * 16 + q4 * 4 + r;
                outf[(size_t)row * 1024 + col] =
                    a[r] + bv + bf2f(resid[(size_t)row * 1024 + col]);
            }
        }
    }
}

// ---------------------------------------------------------------------------
// Attention R25: one block = (head g, 256 q-rows); 8 waves x 32q; 512 thr.
// KVBLK=128: 8 staging iterations; each iteration = two IDENTICAL proven
// 64-key halves (QK^T -> exp->Ps -> PV); Ps reused across halves
// (same-wave in-order LDS dep, proven across iterations since R19).
// LDS 160 KB exact: Ks[2][128key x 128d] + Vt[2][128d x 128key] + Ps[256x64].
// 2-deep counted-vmcnt (8 loads/stage -> vmcnt(8)), setprio, W-layout V.
// XCD head-grouping: XCD x owns heads 8x..8x+7 (4 q-blocks each).
// ---------------------------------------------------------------------------
__device__ __forceinline__ void attn_stage(const ushort* __restrict__ Kh,
                                           const ushort* __restrict__ Wg,
                                           int kt, ushort* KsD, ushort* VtD,
                                           int tid) {
    // K: [128 key][128 d], 2048 chunks, XOR-16 within key-row
#pragma unroll
    for (int i = 0; i < 4; i++) {
        int linear = i * 512 + tid;          // 0..2047
        int r = linear >> 4, p = linear & 15;
        int l = p ^ (r & 15);
        gload_lds16(&Kh[(size_t)(kt * 128 + r) * 128 + l * 8], &KsD[linear * 8]);
    }
    // V: [128 d][half 0/1][8 chunks]; phys p: half=p>>3, pl=p&7, cl=pl^(d&7)
    // source chunk (half, s7=cl) = Wg[d*1024 + cl*128 + kt*16 + half*8]
#pragma unroll
    for (int i = 0; i < 4; i++) {
        int linear = i * 512 + tid;          // 0..2047
        int d = linear >> 4, p = linear & 15;
        int half = p >> 3, pl = p & 7;
        int cl = pl ^ (d & 7);
        gload_lds16(&Wg[(size_t)d * 1024 + cl * 128 + kt * 16 + half * 8],
                    &VtD[linear * 8]);
    }
}

__global__ __launch_bounds__(512) void attn_kernel(
    const ushort* __restrict__ qb, const ushort* __restrict__ kb,
    const ushort* __restrict__ wv, ushort* __restrict__ ob) {
    // XCD head-grouping: XCD x (bid&7) owns heads 8x..8x+7, 4 q-blocks each.
    int bid = blockIdx.x;
    int xcd = bid & 7, ii = bid >> 3;        // ii 0..31
    int g = xcd * 8 + (ii >> 2);             // head 0..63
    int qblk = ii & 3;                       // 256-row q block
    const ushort* Qh = qb + (size_t)g * 131072;
    const ushort* Kh = kb + (size_t)g * 131072;
    const ushort* Wg = wv + (size_t)g * 131072;  // [128 d][8 s7][128 off]

    __shared__ __align__(16) ushort Ks[2][128 * 128];  // 64 KB
    __shared__ __align__(16) ushort Vt[2][128 * 128];  // 64 KB
    __shared__ __align__(16) ushort Ps[256 * 64];      // 32 KB

    int tid = threadIdx.x, lane = tid & 63, w = tid >> 6;  // w in [0,8)
    int l15 = lane & 15, q4 = lane >> 4;
    int q0 = qblk * 256;

    // Q A-fragments for 2 sub-blocks: rows q0 + w*32 + sub*16 + l15
    short8 qf[2][4];
#pragma unroll
    for (int sub = 0; sub < 2; sub++)
#pragma unroll
        for (int ks = 0; ks < 4; ks++)
            qf[sub][ks] = *(const short8*)&Qh[
                (size_t)(q0 + w * 32 + sub * 16 + l15) * 128 + ks * 32 + q4 * 8];

    f32x4 zero = {0.f, 0.f, 0.f, 0.f};
    f32x4 o[2][8];
#pragma unroll
    for (int sub = 0; sub < 2; sub++)
#pragma unroll
        for (int ni = 0; ni < 8; ni++) o[sub][ni] = zero;
    float plsum[2][4] = {{0.f, 0.f, 0.f, 0.f}, {0.f, 0.f, 0.f, 0.f}};

    // prologue: stage kt0 -> buf0, kt1 -> buf1; wait only kt0 (8 left)
    attn_stage(Kh, Wg, 0, &Ks[0][0], &Vt[0][0], tid);
    attn_stage(Kh, Wg, 1, &Ks[1][0], &Vt[1][0], tid);
    asm volatile("s_waitcnt vmcnt(8)" ::: "memory");
    __builtin_amdgcn_s_barrier();

    for (int kt = 0; kt < 8; kt++) {
        const int cur = kt & 1;
        const ushort* Kc = &Ks[cur][0];
        const ushort* Vc = &Vt[cur][0];

        // two identical 64-key halves (keys h*64 .. h*64+63 of this tile)
#pragma unroll
        for (int h = 0; h < 2; h++) {
            // S = Q K^T : 32q x 64key per wave; K frag shared across subs
            f32x4 sacc[2][4];
#pragma unroll
            for (int sub = 0; sub < 2; sub++)
#pragma unroll
                for (int ni = 0; ni < 4; ni++) sacc[sub][ni] = zero;
            __builtin_amdgcn_s_setprio(1);
#pragma unroll
            for (int ks = 0; ks < 4; ks++) {
#pragma unroll
                for (int ni = 0; ni < 4; ni++) {
                    int r = h * 64 + ni * 16 + l15;
                    int p = (ks * 4 + q4) ^ (r & 15);
                    short8 bF = *(const short8*)&Kc[r * 128 + p * 8];
#pragma unroll
                    for (int sub = 0; sub < 2; sub++)
                        sacc[sub][ni] = __builtin_amdgcn_mfma_f32_16x16x32_bf16(
                            qf[sub][ks], bF, sacc[sub][ni], 0, 0, 0);
                }
            }
            __builtin_amdgcn_s_setprio(0);

            // P = exp(S) -> Ps at slot (key&7)*8+(key>>3) (W chunk semantics)
#pragma unroll
            for (int sub = 0; sub < 2; sub++)
#pragma unroll
                for (int ni = 0; ni < 4; ni++) {
#pragma unroll
                    for (int r = 0; r < 4; r++) {
                        float pv = __expf(sacc[sub][ni][r]);
                        plsum[sub][r] += pv;
                        int qloc = w * 32 + sub * 16 + q4 * 4 + r;  // wave-priv
                        int key = ni * 16 + l15;
                        int pc = (key & 7) ^ (qloc & 7);
                        Ps[qloc * 64 + pc * 8 + (key >> 3)] = f2bf(pv);
                    }
                }

            // O += P V  (V frag shared across subs; half-offset h*64 keys)
            __builtin_amdgcn_s_setprio(1);
#pragma unroll
            for (int ks2 = 0; ks2 < 2; ks2++) {
                int c = ks2 * 4 + q4;
                short8 aF[2];
#pragma unroll
                for (int sub = 0; sub < 2; sub++) {
                    int row = w * 32 + sub * 16 + l15;        // row&7 == l15&7
                    aF[sub] = *(const short8*)&Ps[row * 64 + (c ^ (l15 & 7)) * 8];
                }
#pragma unroll
                for (int ni = 0; ni < 8; ni++) {
                    int d = ni * 16 + l15;
                    short8 bF = *(const short8*)&Vc[d * 128 + h * 64 + (c ^ (d & 7)) * 8];
#pragma unroll
                    for (int sub = 0; sub < 2; sub++)
                        o[sub][ni] = __builtin_amdgcn_mfma_f32_16x16x32_bf16(
                            aF[sub], bF, o[sub][ni], 0, 0, 0);
                }
            }
            __builtin_amdgcn_s_setprio(0);
        }

        // ---- all LDS reads of buf[cur] done -> restage; counted vmcnt ----
        asm volatile("s_waitcnt lgkmcnt(0)" ::: "memory");
        __builtin_amdgcn_s_barrier();
        if (kt < 6) attn_stage(Kh, Wg, kt + 2, &Ks[cur][0], &Vt[cur][0], tid);
        if (kt < 6)       asm volatile("s_waitcnt vmcnt(8)" ::: "memory");
        else if (kt == 6) asm volatile("s_waitcnt vmcnt(0)" ::: "memory");
        if (kt < 7) __builtin_amdgcn_s_barrier();
    }

    // row sums: reduce per-lane partials over the 16 l15-lanes
#pragma unroll
    for (int sub = 0; sub < 2; sub++)
#pragma unroll
        for (int r = 0; r < 4; r++) {
#pragma unroll
            for (int m = 1; m < 16; m <<= 1)
                plsum[sub][r] += __shfl_xor(plsum[sub][r], m, 16);
        }
#pragma unroll
    for (int sub = 0; sub < 2; sub++) {
        float inv[4];
#pragma unroll
        for (int r = 0; r < 4; r++) inv[r] = 1.0f / plsum[sub][r];
#pragma unroll
        for (int ni = 0; ni < 8; ni++)
#pragma unroll
            for (int r = 0; r < 4; r++) {
                int qrow = q0 + w * 32 + sub * 16 + q4 * 4 + r;
                ob[(size_t)g * 131072 + (size_t)qrow * 128 + ni * 16 + l15] =
                    f2bf(o[sub][ni][r] * inv[r]);
            }
    }
}

// ---------------------------------------------------------------------------
extern "C" void kernel_launch(void* const* d_in, const int* in_sizes, int n_in,
                              void* d_out, int out_size, void* d_ws, size_t ws_size,
                              hipStream_t stream) {
    const float* x     = (const float*)d_in[0];
    const float* ln_g  = (const float*)d_in[1];
    const float* ln_b  = (const float*)d_in[2];
    const float* w_qkv = (const float*)d_in[3];
    const float* b_qkv = (const float*)d_in[4];
    const float* w_out = (const float*)d_in[5];
    const float* b_out = (const float*)d_in[6];
    float* out = (float*)d_out;

    const size_t MC = 8192ull * 1024ull;  // 8.39M elems
    ushort* xn    = (ushort*)d_ws;
    ushort* wqkvT = xn + MC;
    ushort* woutT = wqkvT + 3072ull * 1024ull;
    ushort* qbuf  = woutT + 1024ull * 1024ull;
    ushort* kbuf  = qbuf + MC;
    ushort* vtbuf = kbuf + MC;        // W: V in [g][d][s7][off] layout
    ushort* attnb = vtbuf + MC;       // attn output
    // total: 46.14M ushorts = 92.3 MB (same layout as passing rounds)

    prep_kernel<<<6144, 256, 0, stream>>>(x, ln_g, ln_b, xn, w_qkv, wqkvT, w_out, woutT);
    // q,k -> qbuf,kbuf ; v -> vtbuf in W layout (transpose_head eliminated)
    gemm_qkv<<<1536, 256, 0, stream>>>(xn, wqkvT, b_qkv, qbuf, kbuf, vtbuf);
    attn_kernel<<<256, 512, 0, stream>>>(qbuf, kbuf, vtbuf, attnb);
    gemm_out<<<512, 256, 0, stream>>>(attnb, woutT, b_out, xn, out);
}